// Round 2
// baseline (1605.857 us; speedup 1.0000x reference)
//
#include <hip/hip_runtime.h>
#include <cstdint>
#include <cstddef>

// ---------------- problem constants ----------------
#define BB   8
#define LLEN 2048
#define DSZ  1024
#define FFN  4096
#define MROWS (BB*LLEN)   // 16384
#define EPSLN 1e-5f

typedef __bf16 bh8 __attribute__((ext_vector_type(8)));
typedef float  f32x4 __attribute__((ext_vector_type(4)));

__device__ __forceinline__ unsigned short f32_to_bf16(float f) {
  unsigned int u = __float_as_uint(f);
  u += 0x7FFFu + ((u >> 16) & 1u);   // round-to-nearest-even
  return (unsigned short)(u >> 16);
}
__device__ __forceinline__ float bf16_to_f32(unsigned short u) {
  return __uint_as_float(((unsigned int)u) << 16);
}

__device__ __forceinline__ void load_lds16(const void* g, void* l) {
  __builtin_amdgcn_global_load_lds((const __attribute__((address_space(1))) void*)g,
                                   (__attribute__((address_space(3))) void*)l, 16, 0, 0);
}

// ---------------- weight transpose + f32->bf16 ----------------
// W: K x N (f32, row-major)  ->  Wt: N x K (bf16, row-major)
__global__ __launch_bounds__(256) void transpose_bf16(const float* __restrict__ W,
                                                      unsigned short* __restrict__ Wt,
                                                      int K, int N) {
  __shared__ float tile[32][33];
  int n0 = blockIdx.x * 32, k0 = blockIdx.y * 32;
  int tx = threadIdx.x, ty = threadIdx.y;   // block (32,8)
#pragma unroll
  for (int j = 0; j < 32; j += 8)
    tile[ty + j][tx] = W[(size_t)(k0 + ty + j) * N + n0 + tx];
  __syncthreads();
#pragma unroll
  for (int j = 0; j < 32; j += 8)
    Wt[(size_t)(n0 + ty + j) * K + k0 + tx] = f32_to_bf16(tile[tx][ty + j]);
}

// ---------------- fused LayerNorm + time-shift mix (att: 3 outputs) ----------------
// each block handles one row (b,t): computes LN(x[t]) and LN(x[t-1]) then mixes.
__global__ __launch_bounds__(256) void lnmix_att(const float* __restrict__ x,
                                                 const float* __restrict__ g,
                                                 const float* __restrict__ bb,
                                                 const float* __restrict__ mk,
                                                 const float* __restrict__ mv,
                                                 const float* __restrict__ mr,
                                                 unsigned short* __restrict__ xk,
                                                 unsigned short* __restrict__ xv,
                                                 unsigned short* __restrict__ xr) {
  int row = blockIdx.x;
  int t = row & (LLEN - 1);
  int tid = threadIdx.x;
  float4 vc = ((const float4*)(x + (size_t)row * DSZ))[tid];
  float4 vp = make_float4(0.f, 0.f, 0.f, 0.f);
  if (t > 0) vp = ((const float4*)(x + (size_t)(row - 1) * DSZ))[tid];
  float sc = vc.x + vc.y + vc.z + vc.w;
  float qc = vc.x * vc.x + vc.y * vc.y + vc.z * vc.z + vc.w * vc.w;
  float sp = vp.x + vp.y + vp.z + vp.w;
  float qp = vp.x * vp.x + vp.y * vp.y + vp.z * vp.z + vp.w * vp.w;
#pragma unroll
  for (int off = 32; off; off >>= 1) {
    sc += __shfl_down(sc, off); qc += __shfl_down(qc, off);
    sp += __shfl_down(sp, off); qp += __shfl_down(qp, off);
  }
  __shared__ float red[16];
  int lane = tid & 63, w = tid >> 6;
  if (lane == 0) { red[w] = sc; red[4 + w] = qc; red[8 + w] = sp; red[12 + w] = qp; }
  __syncthreads();
  if (tid < 4) red[tid * 4] = red[tid * 4] + red[tid * 4 + 1] + red[tid * 4 + 2] + red[tid * 4 + 3];
  __syncthreads();
  const float invD = 1.f / DSZ;
  float mc = red[0] * invD, rc = rsqrtf(red[4] * invD - mc * mc + EPSLN);
  float mp = red[8] * invD, rp = rsqrtf(red[12] * invD - mp * mp + EPSLN);
  float4 G = ((const float4*)g)[tid], Bv = ((const float4*)bb)[tid];
  float c[4] = { vc.x, vc.y, vc.z, vc.w };
  float p[4] = { vp.x, vp.y, vp.z, vp.w };
  float Ga[4] = { G.x, G.y, G.z, G.w };
  float Ba[4] = { Bv.x, Bv.y, Bv.z, Bv.w };
  float4 K = ((const float4*)mk)[tid];
  float4 V = ((const float4*)mv)[tid];
  float4 R = ((const float4*)mr)[tid];
  float Ka[4] = { K.x, K.y, K.z, K.w };
  float Va[4] = { V.x, V.y, V.z, V.w };
  float Ra[4] = { R.x, R.y, R.z, R.w };
  ushort4 ok, ov, orr;
  unsigned short* okp = &ok.x; unsigned short* ovp = &ov.x; unsigned short* orp = &orr.x;
#pragma unroll
  for (int e = 0; e < 4; ++e) {
    float hc = (c[e] - mc) * rc * Ga[e] + Ba[e];
    float hp = (t > 0) ? (p[e] - mp) * rp * Ga[e] + Ba[e] : 0.f;
    okp[e] = f32_to_bf16(hc * Ka[e] + hp * (1.f - Ka[e]));
    ovp[e] = f32_to_bf16(hc * Va[e] + hp * (1.f - Va[e]));
    orp[e] = f32_to_bf16(hc * Ra[e] + hp * (1.f - Ra[e]));
  }
  size_t e4 = (size_t)row * DSZ + tid * 4;
  *(ushort4*)(xk + e4) = ok;
  *(ushort4*)(xv + e4) = ov;
  *(ushort4*)(xr + e4) = orr;
}

// ---------------- fused LayerNorm + time-shift mix (ffn: 2 outputs) ----------------
__global__ __launch_bounds__(256) void lnmix_ffn(const float* __restrict__ x,
                                                 const float* __restrict__ g,
                                                 const float* __restrict__ bb,
                                                 const float* __restrict__ mk,
                                                 const float* __restrict__ mr,
                                                 unsigned short* __restrict__ xk,
                                                 unsigned short* __restrict__ xr) {
  int row = blockIdx.x;
  int t = row & (LLEN - 1);
  int tid = threadIdx.x;
  float4 vc = ((const float4*)(x + (size_t)row * DSZ))[tid];
  float4 vp = make_float4(0.f, 0.f, 0.f, 0.f);
  if (t > 0) vp = ((const float4*)(x + (size_t)(row - 1) * DSZ))[tid];
  float sc = vc.x + vc.y + vc.z + vc.w;
  float qc = vc.x * vc.x + vc.y * vc.y + vc.z * vc.z + vc.w * vc.w;
  float sp = vp.x + vp.y + vp.z + vp.w;
  float qp = vp.x * vp.x + vp.y * vp.y + vp.z * vp.z + vp.w * vp.w;
#pragma unroll
  for (int off = 32; off; off >>= 1) {
    sc += __shfl_down(sc, off); qc += __shfl_down(qc, off);
    sp += __shfl_down(sp, off); qp += __shfl_down(qp, off);
  }
  __shared__ float red[16];
  int lane = tid & 63, w = tid >> 6;
  if (lane == 0) { red[w] = sc; red[4 + w] = qc; red[8 + w] = sp; red[12 + w] = qp; }
  __syncthreads();
  if (tid < 4) red[tid * 4] = red[tid * 4] + red[tid * 4 + 1] + red[tid * 4 + 2] + red[tid * 4 + 3];
  __syncthreads();
  const float invD = 1.f / DSZ;
  float mc = red[0] * invD, rc = rsqrtf(red[4] * invD - mc * mc + EPSLN);
  float mp = red[8] * invD, rp = rsqrtf(red[12] * invD - mp * mp + EPSLN);
  float4 G = ((const float4*)g)[tid], Bv = ((const float4*)bb)[tid];
  float c[4] = { vc.x, vc.y, vc.z, vc.w };
  float p[4] = { vp.x, vp.y, vp.z, vp.w };
  float Ga[4] = { G.x, G.y, G.z, G.w };
  float Ba[4] = { Bv.x, Bv.y, Bv.z, Bv.w };
  float4 K = ((const float4*)mk)[tid];
  float4 R = ((const float4*)mr)[tid];
  float Ka[4] = { K.x, K.y, K.z, K.w };
  float Ra[4] = { R.x, R.y, R.z, R.w };
  ushort4 ok, orr;
  unsigned short* okp = &ok.x; unsigned short* orp = &orr.x;
#pragma unroll
  for (int e = 0; e < 4; ++e) {
    float hc = (c[e] - mc) * rc * Ga[e] + Ba[e];
    float hp = (t > 0) ? (p[e] - mp) * rp * Ga[e] + Ba[e] : 0.f;
    okp[e] = f32_to_bf16(hc * Ka[e] + hp * (1.f - Ka[e]));
    orp[e] = f32_to_bf16(hc * Ra[e] + hp * (1.f - Ra[e]));
  }
  size_t e4 = (size_t)row * DSZ + tid * 4;
  *(ushort4*)(xk + e4) = ok;
  *(ushort4*)(xr + e4) = orr;
}

// ---------------- WKV recurrence (one thread per (b,d)), bf16 in/out ----------------
__global__ __launch_bounds__(256) void wkv_kernel(const unsigned short* __restrict__ kk,
                                                  const unsigned short* __restrict__ vv,
                                                  const unsigned short* __restrict__ rr,
                                                  const float* __restrict__ td,
                                                  const float* __restrict__ tf,
                                                  unsigned short* __restrict__ rw) {
  int idx = blockIdx.x * 256 + threadIdx.x;   // 0..8191
  int d = idx & (DSZ - 1);
  int b = idx >> 10;
  float w = -expf(td[d]);
  float u = tf[d];
  size_t base = (size_t)b * LLEN * DSZ + d;
  float p = 0.f, q = 0.f, o = -1e38f;
  float kt = bf16_to_f32(kk[base]);
  float vt = bf16_to_f32(vv[base]);
  float rt = bf16_to_f32(rr[base]);
  for (int t = 0; t < LLEN; ++t) {
    float kn = 0.f, vn = 0.f, rn = 0.f;
    if (t < LLEN - 1) {
      size_t nxt = base + ((size_t)(t + 1) << 10);
      kn = bf16_to_f32(kk[nxt]); vn = bf16_to_f32(vv[nxt]); rn = bf16_to_f32(rr[nxt]);
    }
    float uk = u + kt;
    float no = fmaxf(o, uk);
    float A  = expf(o - no);
    float Bc = expf(uk - no);
    float out = (A * p + Bc * vt) / (A * q + Bc);
    float ow  = o + w;
    float no2 = fmaxf(ow, kt);
    float A2  = expf(ow - no2);
    float B2  = expf(kt - no2);
    p = A2 * p + B2 * vt;
    q = A2 * q + B2;
    o = no2;
    rw[base + ((size_t)t << 10)] = f32_to_bf16(rt * out);
    kt = kn; vt = vn; rt = rn;
  }
}

// ---------------- bf16 MFMA GEMM: C(MxN) = A(MxK) * Bt(NxK)^T ----------------
// EPI: 0 Cbf=bf16(acc) | 1 Cbf=bf16(sigmoid(acc)) | 2 C=aux1+acc
//      3 Cbf=bf16(relu(acc)^2) | 4 C=aux1+bf16(aux2b)*acc
#define BM 128
#define BN 128
#define BKK 32
template <int EPI>
__global__ __launch_bounds__(256) void gemm_bt(const unsigned short* __restrict__ A,
                                               const unsigned short* __restrict__ Bt,
                                               float* __restrict__ C,
                                               unsigned short* __restrict__ Cbf,
                                               const float* __restrict__ aux1,
                                               const unsigned short* __restrict__ aux2b,
                                               int M, int N, int K) {
  __shared__ unsigned short As[BM * BKK];   // 8 KB
  __shared__ unsigned short Bs[BN * BKK];   // 8 KB
  int tid  = threadIdx.x;
  int lane = tid & 63, w = tid >> 6;
  int wm = w >> 1, wn = w & 1;              // 2x2 waves, 64x64 each
  int bm = blockIdx.y, bn = blockIdx.x;

  f32x4 acc[4][4];
#pragma unroll
  for (int i = 0; i < 4; ++i)
#pragma unroll
    for (int j = 0; j < 4; ++j)
#pragma unroll
      for (int e = 0; e < 4; ++e) acc[i][j][e] = 0.f;

  const unsigned short* Ablk = A  + (size_t)bm * BM * K;
  const unsigned short* Bblk = Bt + (size_t)bn * BN * K;

  int c0 = tid, c1 = tid + 256;             // 16B chunks of the 8KB tile
  int ar0 = c0 >> 2, ac0 = (c0 & 3) * 8;
  int ar1 = c1 >> 2, ac1 = (c1 & 3) * 8;

  int krow = (lane >> 4) * 8;
  int r16  = lane & 15;

  int nk = K / BKK;
  for (int kt = 0; kt < nk; ++kt) {
    int kb = kt * BKK;
    load_lds16(Ablk + (size_t)ar0 * K + kb + ac0, &As[c0 * 8]);
    load_lds16(Ablk + (size_t)ar1 * K + kb + ac1, &As[c1 * 8]);
    load_lds16(Bblk + (size_t)ar0 * K + kb + ac0, &Bs[c0 * 8]);
    load_lds16(Bblk + (size_t)ar1 * K + kb + ac1, &Bs[c1 * 8]);
    __syncthreads();
    bh8 afrag[4], bfrag[4];
#pragma unroll
    for (int i = 0; i < 4; ++i) {
      afrag[i] = *(const bh8*)&As[(wm * 64 + i * 16 + r16) * BKK + krow];
      bfrag[i] = *(const bh8*)&Bs[(wn * 64 + i * 16 + r16) * BKK + krow];
    }
#pragma unroll
    for (int i = 0; i < 4; ++i)
#pragma unroll
      for (int j = 0; j < 4; ++j)
        acc[i][j] = __builtin_amdgcn_mfma_f32_16x16x32_bf16(afrag[i], bfrag[j], acc[i][j], 0, 0, 0);
    __syncthreads();
  }

  int r4 = (lane >> 4) * 4, cn = lane & 15;
#pragma unroll
  for (int i = 0; i < 4; ++i) {
#pragma unroll
    for (int j = 0; j < 4; ++j) {
      int col = bn * BN + wn * 64 + j * 16 + cn;
#pragma unroll
      for (int rr = 0; rr < 4; ++rr) {
        int row = bm * BM + wm * 64 + i * 16 + r4 + rr;
        size_t idx = (size_t)row * N + col;
        float val = acc[i][j][rr];
        if (EPI == 0) {
          Cbf[idx] = f32_to_bf16(val);
        } else if (EPI == 1) {
          Cbf[idx] = f32_to_bf16(1.f / (1.f + expf(-val)));
        } else if (EPI == 2) {
          C[idx] = aux1[idx] + val;
        } else if (EPI == 3) {
          float t = val > 0.f ? val : 0.f;
          Cbf[idx] = f32_to_bf16(t * t);
        } else {
          C[idx] = aux1[idx] + bf16_to_f32(aux2b[idx]) * val;
        }
      }
    }
  }
}

// ---------------- host launcher ----------------
extern "C" void kernel_launch(void* const* d_in, const int* in_sizes, int n_in,
                              void* d_out, int out_size, void* d_ws, size_t ws_size,
                              hipStream_t stream) {
  const float* x        = (const float*)d_in[0];
  const float* ln_att_g = (const float*)d_in[1];
  const float* ln_att_b = (const float*)d_in[2];
  const float* ln_ffn_g = (const float*)d_in[3];
  const float* ln_ffn_b = (const float*)d_in[4];
  const float* td       = (const float*)d_in[5];
  const float* tf       = (const float*)d_in[6];
  const float* amk      = (const float*)d_in[7];
  const float* amv      = (const float*)d_in[8];
  const float* amr      = (const float*)d_in[9];
  const float* att_wk   = (const float*)d_in[10];
  const float* att_wv   = (const float*)d_in[11];
  const float* att_wr   = (const float*)d_in[12];
  const float* att_wo   = (const float*)d_in[13];
  const float* fmk      = (const float*)d_in[14];
  const float* fmr      = (const float*)d_in[15];
  const float* ffn_wk   = (const float*)d_in[16];
  const float* ffn_wv   = (const float*)d_in[17];
  const float* ffn_wr   = (const float*)d_in[18];
  float* out = (float*)d_out;
  (void)in_sizes; (void)n_in; (void)out_size;

  // ---- workspace budget check (leave output zero if insufficient -> clean fail) ----
  const size_t WBYTES  = 4 * ((size_t)DSZ * DSZ * 2)      // wkT wvT wrT woT
                       + (size_t)FFN * DSZ * 2            // fwkT
                       + (size_t)DSZ * FFN * 2            // fwvT
                       + (size_t)DSZ * DSZ * 2;           // fwrT
  const size_t BUF     = (size_t)MROWS * DSZ * 2;         // 32 MB bf16
  const size_t NEEDED  = WBYTES + 4 * BUF + 2 * BUF;      // A,B,C,D + E(64MB)
  if (ws_size < NEEDED) return;

  char* ws = (char*)d_ws;
  size_t off = 0;
  auto take = [&](size_t bytes) { char* p = ws + off; off += (bytes + 255) & ~(size_t)255; return p; };

  unsigned short* wkT  = (unsigned short*)take((size_t)DSZ * DSZ * 2);
  unsigned short* wvT  = (unsigned short*)take((size_t)DSZ * DSZ * 2);
  unsigned short* wrT  = (unsigned short*)take((size_t)DSZ * DSZ * 2);
  unsigned short* woT  = (unsigned short*)take((size_t)DSZ * DSZ * 2);
  unsigned short* fwkT = (unsigned short*)take((size_t)FFN * DSZ * 2);  // 4096 x 1024
  unsigned short* fwvT = (unsigned short*)take((size_t)DSZ * FFN * 2);  // 1024 x 4096
  unsigned short* fwrT = (unsigned short*)take((size_t)DSZ * DSZ * 2);
  unsigned short* bufA = (unsigned short*)take(BUF);
  unsigned short* bufB = (unsigned short*)take(BUF);
  unsigned short* bufC = (unsigned short*)take(BUF);
  unsigned short* bufD = (unsigned short*)take(BUF);
  (void)take(2 * BUF);                                    // E: extension for kf
  unsigned short* kf = bufC;                              // spans C + D + E = 128 MB

  dim3 tb(32, 8);
  transpose_bf16<<<dim3(DSZ / 32, DSZ / 32), tb, 0, stream>>>(att_wk, wkT, DSZ, DSZ);
  transpose_bf16<<<dim3(DSZ / 32, DSZ / 32), tb, 0, stream>>>(att_wv, wvT, DSZ, DSZ);
  transpose_bf16<<<dim3(DSZ / 32, DSZ / 32), tb, 0, stream>>>(att_wr, wrT, DSZ, DSZ);
  transpose_bf16<<<dim3(DSZ / 32, DSZ / 32), tb, 0, stream>>>(att_wo, woT, DSZ, DSZ);
  transpose_bf16<<<dim3(FFN / 32, DSZ / 32), tb, 0, stream>>>(ffn_wk, fwkT, DSZ, FFN);
  transpose_bf16<<<dim3(DSZ / 32, FFN / 32), tb, 0, stream>>>(ffn_wv, fwvT, FFN, DSZ);
  transpose_bf16<<<dim3(DSZ / 32, DSZ / 32), tb, 0, stream>>>(ffn_wr, fwrT, DSZ, DSZ);

  // --- attention branch ---
  // A=xk B=xv C=xr
  lnmix_att<<<MROWS, 256, 0, stream>>>(x, ln_att_g, ln_att_b, amk, amv, amr, bufA, bufB, bufC);
  // D=k, A free -> v into A, B free -> r into B, C free -> rw into C
  gemm_bt<0><<<dim3(DSZ / BN, MROWS / BM), 256, 0, stream>>>(bufA, wkT, nullptr, bufD, nullptr, nullptr, MROWS, DSZ, DSZ);
  gemm_bt<0><<<dim3(DSZ / BN, MROWS / BM), 256, 0, stream>>>(bufB, wvT, nullptr, bufA, nullptr, nullptr, MROWS, DSZ, DSZ);
  gemm_bt<1><<<dim3(DSZ / BN, MROWS / BM), 256, 0, stream>>>(bufC, wrT, nullptr, bufB, nullptr, nullptr, MROWS, DSZ, DSZ);
  wkv_kernel<<<(BB * DSZ) / 256, 256, 0, stream>>>(bufD, bufA, bufB, td, tf, bufC);
  gemm_bt<2><<<dim3(DSZ / BN, MROWS / BM), 256, 0, stream>>>(bufC, woT, out, nullptr, x, nullptr, MROWS, DSZ, DSZ);

  // --- ffn branch ---
  // A=xk2 B=xr2
  lnmix_ffn<<<MROWS, 256, 0, stream>>>(out, ln_ffn_g, ln_ffn_b, fmk, fmr, bufA, bufB);
  // kf = C..E (128 MB)
  gemm_bt<3><<<dim3(FFN / BN, MROWS / BM), 256, 0, stream>>>(bufA, fwkT, nullptr, kf, nullptr, nullptr, MROWS, FFN, DSZ);
  // rf -> A (bf16)
  gemm_bt<1><<<dim3(DSZ / BN, MROWS / BM), 256, 0, stream>>>(bufB, fwrT, nullptr, bufA, nullptr, nullptr, MROWS, DSZ, DSZ);
  // out = out + rf * (kf @ ffn_wv)
  gemm_bt<4><<<dim3(DSZ / BN, MROWS / BM), 256, 0, stream>>>(kf, fwvT, out, nullptr, out, bufA, MROWS, DSZ, FFN);
}

// Round 3
// 944.729 us; speedup vs baseline: 1.6998x; 1.6998x over previous
//
#include <hip/hip_runtime.h>
#include <cstdint>
#include <cstddef>

// ---------------- problem constants ----------------
#define BB   8
#define LLEN 2048
#define DSZ  1024
#define FFN  4096
#define MROWS (BB*LLEN)   // 16384
#define EPSLN 1e-5f
#define WKV_C 32          // chunks along L
#define WKV_S (LLEN/WKV_C) // 64 steps per chunk
#define WKV_STATES (BB*WKV_C*DSZ)  // 262144

typedef __bf16 bh8 __attribute__((ext_vector_type(8)));
typedef float  f32x4 __attribute__((ext_vector_type(4)));

__device__ __forceinline__ unsigned short f32_to_bf16(float f) {
  unsigned int u = __float_as_uint(f);
  u += 0x7FFFu + ((u >> 16) & 1u);   // round-to-nearest-even
  return (unsigned short)(u >> 16);
}
__device__ __forceinline__ float bf16_to_f32(unsigned short u) {
  return __uint_as_float(((unsigned int)u) << 16);
}

__device__ __forceinline__ void load_lds16(const void* g, void* l) {
  __builtin_amdgcn_global_load_lds((const __attribute__((address_space(1))) void*)g,
                                   (__attribute__((address_space(3))) void*)l, 16, 0, 0);
}

// ---------------- weight transpose + f32->bf16 ----------------
// W: K x N (f32, row-major)  ->  Wt: N x K (bf16, row-major)
__global__ __launch_bounds__(256) void transpose_bf16(const float* __restrict__ W,
                                                      unsigned short* __restrict__ Wt,
                                                      int K, int N) {
  __shared__ float tile[32][33];
  int n0 = blockIdx.x * 32, k0 = blockIdx.y * 32;
  int tx = threadIdx.x, ty = threadIdx.y;   // block (32,8)
#pragma unroll
  for (int j = 0; j < 32; j += 8)
    tile[ty + j][tx] = W[(size_t)(k0 + ty + j) * N + n0 + tx];
  __syncthreads();
#pragma unroll
  for (int j = 0; j < 32; j += 8)
    Wt[(size_t)(n0 + ty + j) * K + k0 + tx] = f32_to_bf16(tile[tx][ty + j]);
}

// ---------------- fused LayerNorm + time-shift mix (att: 3 outputs) ----------------
__global__ __launch_bounds__(256) void lnmix_att(const float* __restrict__ x,
                                                 const float* __restrict__ g,
                                                 const float* __restrict__ bb,
                                                 const float* __restrict__ mk,
                                                 const float* __restrict__ mv,
                                                 const float* __restrict__ mr,
                                                 unsigned short* __restrict__ xk,
                                                 unsigned short* __restrict__ xv,
                                                 unsigned short* __restrict__ xr) {
  int row = blockIdx.x;
  int t = row & (LLEN - 1);
  int tid = threadIdx.x;
  float4 vc = ((const float4*)(x + (size_t)row * DSZ))[tid];
  float4 vp = make_float4(0.f, 0.f, 0.f, 0.f);
  if (t > 0) vp = ((const float4*)(x + (size_t)(row - 1) * DSZ))[tid];
  float sc = vc.x + vc.y + vc.z + vc.w;
  float qc = vc.x * vc.x + vc.y * vc.y + vc.z * vc.z + vc.w * vc.w;
  float sp = vp.x + vp.y + vp.z + vp.w;
  float qp = vp.x * vp.x + vp.y * vp.y + vp.z * vp.z + vp.w * vp.w;
#pragma unroll
  for (int off = 32; off; off >>= 1) {
    sc += __shfl_down(sc, off); qc += __shfl_down(qc, off);
    sp += __shfl_down(sp, off); qp += __shfl_down(qp, off);
  }
  __shared__ float red[16];
  int lane = tid & 63, w = tid >> 6;
  if (lane == 0) { red[w] = sc; red[4 + w] = qc; red[8 + w] = sp; red[12 + w] = qp; }
  __syncthreads();
  if (tid < 4) red[tid * 4] = red[tid * 4] + red[tid * 4 + 1] + red[tid * 4 + 2] + red[tid * 4 + 3];
  __syncthreads();
  const float invD = 1.f / DSZ;
  float mc = red[0] * invD, rc = rsqrtf(red[4] * invD - mc * mc + EPSLN);
  float mp = red[8] * invD, rp = rsqrtf(red[12] * invD - mp * mp + EPSLN);
  float4 G = ((const float4*)g)[tid], Bv = ((const float4*)bb)[tid];
  float c[4] = { vc.x, vc.y, vc.z, vc.w };
  float p[4] = { vp.x, vp.y, vp.z, vp.w };
  float Ga[4] = { G.x, G.y, G.z, G.w };
  float Ba[4] = { Bv.x, Bv.y, Bv.z, Bv.w };
  float4 K = ((const float4*)mk)[tid];
  float4 V = ((const float4*)mv)[tid];
  float4 R = ((const float4*)mr)[tid];
  float Ka[4] = { K.x, K.y, K.z, K.w };
  float Va[4] = { V.x, V.y, V.z, V.w };
  float Ra[4] = { R.x, R.y, R.z, R.w };
  ushort4 ok, ov, orr;
  unsigned short* okp = &ok.x; unsigned short* ovp = &ov.x; unsigned short* orp = &orr.x;
#pragma unroll
  for (int e = 0; e < 4; ++e) {
    float hc = (c[e] - mc) * rc * Ga[e] + Ba[e];
    float hp = (t > 0) ? (p[e] - mp) * rp * Ga[e] + Ba[e] : 0.f;
    okp[e] = f32_to_bf16(hc * Ka[e] + hp * (1.f - Ka[e]));
    ovp[e] = f32_to_bf16(hc * Va[e] + hp * (1.f - Va[e]));
    orp[e] = f32_to_bf16(hc * Ra[e] + hp * (1.f - Ra[e]));
  }
  size_t e4 = (size_t)row * DSZ + tid * 4;
  *(ushort4*)(xk + e4) = ok;
  *(ushort4*)(xv + e4) = ov;
  *(ushort4*)(xr + e4) = orr;
}

// ---------------- fused LayerNorm + time-shift mix (ffn: 2 outputs) ----------------
__global__ __launch_bounds__(256) void lnmix_ffn(const float* __restrict__ x,
                                                 const float* __restrict__ g,
                                                 const float* __restrict__ bb,
                                                 const float* __restrict__ mk,
                                                 const float* __restrict__ mr,
                                                 unsigned short* __restrict__ xk,
                                                 unsigned short* __restrict__ xr) {
  int row = blockIdx.x;
  int t = row & (LLEN - 1);
  int tid = threadIdx.x;
  float4 vc = ((const float4*)(x + (size_t)row * DSZ))[tid];
  float4 vp = make_float4(0.f, 0.f, 0.f, 0.f);
  if (t > 0) vp = ((const float4*)(x + (size_t)(row - 1) * DSZ))[tid];
  float sc = vc.x + vc.y + vc.z + vc.w;
  float qc = vc.x * vc.x + vc.y * vc.y + vc.z * vc.z + vc.w * vc.w;
  float sp = vp.x + vp.y + vp.z + vp.w;
  float qp = vp.x * vp.x + vp.y * vp.y + vp.z * vp.z + vp.w * vp.w;
#pragma unroll
  for (int off = 32; off; off >>= 1) {
    sc += __shfl_down(sc, off); qc += __shfl_down(qc, off);
    sp += __shfl_down(sp, off); qp += __shfl_down(qp, off);
  }
  __shared__ float red[16];
  int lane = tid & 63, w = tid >> 6;
  if (lane == 0) { red[w] = sc; red[4 + w] = qc; red[8 + w] = sp; red[12 + w] = qp; }
  __syncthreads();
  if (tid < 4) red[tid * 4] = red[tid * 4] + red[tid * 4 + 1] + red[tid * 4 + 2] + red[tid * 4 + 3];
  __syncthreads();
  const float invD = 1.f / DSZ;
  float mc = red[0] * invD, rc = rsqrtf(red[4] * invD - mc * mc + EPSLN);
  float mp = red[8] * invD, rp = rsqrtf(red[12] * invD - mp * mp + EPSLN);
  float4 G = ((const float4*)g)[tid], Bv = ((const float4*)bb)[tid];
  float c[4] = { vc.x, vc.y, vc.z, vc.w };
  float p[4] = { vp.x, vp.y, vp.z, vp.w };
  float Ga[4] = { G.x, G.y, G.z, G.w };
  float Ba[4] = { Bv.x, Bv.y, Bv.z, Bv.w };
  float4 K = ((const float4*)mk)[tid];
  float4 R = ((const float4*)mr)[tid];
  float Ka[4] = { K.x, K.y, K.z, K.w };
  float Ra[4] = { R.x, R.y, R.z, R.w };
  ushort4 ok, orr;
  unsigned short* okp = &ok.x; unsigned short* orp = &orr.x;
#pragma unroll
  for (int e = 0; e < 4; ++e) {
    float hc = (c[e] - mc) * rc * Ga[e] + Ba[e];
    float hp = (t > 0) ? (p[e] - mp) * rp * Ga[e] + Ba[e] : 0.f;
    okp[e] = f32_to_bf16(hc * Ka[e] + hp * (1.f - Ka[e]));
    orp[e] = f32_to_bf16(hc * Ra[e] + hp * (1.f - Ra[e]));
  }
  size_t e4 = (size_t)row * DSZ + tid * 4;
  *(ushort4*)(xk + e4) = ok;
  *(ushort4*)(xr + e4) = orr;
}

// ---------------- WKV chunked scan ----------------
// pass 1: per (b,chunk,d) local state from zero init (no outputs)
__global__ __launch_bounds__(256) void wkv_pass1(const unsigned short* __restrict__ kk,
                                                 const unsigned short* __restrict__ vv,
                                                 const float* __restrict__ td,
                                                 float* __restrict__ sP,
                                                 float* __restrict__ sQ,
                                                 float* __restrict__ sO) {
  int gid = blockIdx.x * 256 + threadIdx.x;       // (b*C + c)*DSZ + d
  int d  = gid & (DSZ - 1);
  int bc = gid >> 10;
  int c  = bc & (WKV_C - 1);
  int b  = bc >> 5;
  float w = -expf(td[d]);
  size_t base = ((size_t)b * LLEN + (size_t)c * WKV_S) * DSZ + d;
  float p = 0.f, q = 0.f, o = -1e38f;
  float kt = bf16_to_f32(kk[base]);
  float vt = bf16_to_f32(vv[base]);
  for (int t = 0; t < WKV_S; ++t) {
    float kn = 0.f, vn = 0.f;
    if (t < WKV_S - 1) {
      size_t nxt = base + ((size_t)(t + 1) << 10);
      kn = bf16_to_f32(kk[nxt]); vn = bf16_to_f32(vv[nxt]);
    }
    float ow  = o + w;
    float no2 = fmaxf(ow, kt);
    float A2  = expf(ow - no2);
    float B2  = expf(kt - no2);
    p = A2 * p + B2 * vt;
    q = A2 * q + B2;
    o = no2;
    kt = kn; vt = vn;
  }
  sP[gid] = p; sQ[gid] = q; sO[gid] = o;
}

// pass 2: serial combine over chunks -> prefix (incoming) state per chunk
__global__ __launch_bounds__(256) void wkv_combine(const float* __restrict__ sP,
                                                   const float* __restrict__ sQ,
                                                   const float* __restrict__ sO,
                                                   const float* __restrict__ td,
                                                   float* __restrict__ pP,
                                                   float* __restrict__ pQ,
                                                   float* __restrict__ pO) {
  int gid = blockIdx.x * 256 + threadIdx.x;       // (b,d): 0..8191
  int d = gid & (DSZ - 1);
  int b = gid >> 10;
  float w = -expf(td[d]);
  float Sw = (float)WKV_S * w;
  float p = 0.f, q = 0.f, o = -1e38f;
  for (int c = 0; c < WKV_C; ++c) {
    size_t idx = (((size_t)b * WKV_C + c) << 10) + d;
    pP[idx] = p; pQ[idx] = q; pO[idx] = o;
    float lp = sP[idx], lq = sQ[idx], lo = sO[idx];
    float oin = o + Sw;
    float no  = fmaxf(oin, lo);
    float Ai  = expf(oin - no);
    float Al  = expf(lo - no);
    p = Ai * p + Al * lp;
    q = Ai * q + Al * lq;
    o = no;
  }
}

// pass 3: replay chunk from prefix state, emit rw = bf16(r * wkv_out)
__global__ __launch_bounds__(256) void wkv_pass3(const unsigned short* __restrict__ kk,
                                                 const unsigned short* __restrict__ vv,
                                                 const unsigned short* __restrict__ rr,
                                                 const float* __restrict__ td,
                                                 const float* __restrict__ tf,
                                                 const float* __restrict__ pP,
                                                 const float* __restrict__ pQ,
                                                 const float* __restrict__ pO,
                                                 unsigned short* __restrict__ rw) {
  int gid = blockIdx.x * 256 + threadIdx.x;
  int d  = gid & (DSZ - 1);
  int bc = gid >> 10;
  int c  = bc & (WKV_C - 1);
  int b  = bc >> 5;
  float w = -expf(td[d]);
  float u = tf[d];
  float p = pP[gid], q = pQ[gid], o = pO[gid];
  size_t base = ((size_t)b * LLEN + (size_t)c * WKV_S) * DSZ + d;
  float kt = bf16_to_f32(kk[base]);
  float vt = bf16_to_f32(vv[base]);
  float rt = bf16_to_f32(rr[base]);
  for (int t = 0; t < WKV_S; ++t) {
    float kn = 0.f, vn = 0.f, rn = 0.f;
    if (t < WKV_S - 1) {
      size_t nxt = base + ((size_t)(t + 1) << 10);
      kn = bf16_to_f32(kk[nxt]); vn = bf16_to_f32(vv[nxt]); rn = bf16_to_f32(rr[nxt]);
    }
    float uk = u + kt;
    float no = fmaxf(o, uk);
    float A  = expf(o - no);
    float Bc = expf(uk - no);
    float out = (A * p + Bc * vt) / (A * q + Bc);
    rw[base + ((size_t)t << 10)] = f32_to_bf16(rt * out);
    float ow  = o + w;
    float no2 = fmaxf(ow, kt);
    float A2  = expf(ow - no2);
    float B2  = expf(kt - no2);
    p = A2 * p + B2 * vt;
    q = A2 * q + B2;
    o = no2;
    kt = kn; vt = vn; rt = rn;
  }
}

// ---------------- bf16 MFMA GEMM: C(MxN) = A(MxK) * Bt(NxK)^T ----------------
// EPI: 0 Cbf=bf16(acc) | 1 Cbf=bf16(sigmoid(acc)) | 2 C=aux1+acc
//      3 Cbf=bf16(relu(acc)^2) | 4 C=aux1+bf16(aux2b)*acc
#define BM 128
#define BN 128
#define BKK 32
template <int EPI>
__global__ __launch_bounds__(256) void gemm_bt(const unsigned short* __restrict__ A,
                                               const unsigned short* __restrict__ Bt,
                                               float* __restrict__ C,
                                               unsigned short* __restrict__ Cbf,
                                               const float* __restrict__ aux1,
                                               const unsigned short* __restrict__ aux2b,
                                               int M, int N, int K) {
  __shared__ unsigned short As[BM * BKK];   // 8 KB
  __shared__ unsigned short Bs[BN * BKK];   // 8 KB
  int tid  = threadIdx.x;
  int lane = tid & 63, w = tid >> 6;
  int wm = w >> 1, wn = w & 1;              // 2x2 waves, 64x64 each
  int bm = blockIdx.y, bn = blockIdx.x;

  f32x4 acc[4][4];
#pragma unroll
  for (int i = 0; i < 4; ++i)
#pragma unroll
    for (int j = 0; j < 4; ++j)
#pragma unroll
      for (int e = 0; e < 4; ++e) acc[i][j][e] = 0.f;

  const unsigned short* Ablk = A  + (size_t)bm * BM * K;
  const unsigned short* Bblk = Bt + (size_t)bn * BN * K;

  int c0 = tid, c1 = tid + 256;             // 16B chunks of the 8KB tile
  int ar0 = c0 >> 2, ac0 = (c0 & 3) * 8;
  int ar1 = c1 >> 2, ac1 = (c1 & 3) * 8;

  int krow = (lane >> 4) * 8;
  int r16  = lane & 15;

  int nk = K / BKK;
  for (int kt = 0; kt < nk; ++kt) {
    int kb = kt * BKK;
    load_lds16(Ablk + (size_t)ar0 * K + kb + ac0, &As[c0 * 8]);
    load_lds16(Ablk + (size_t)ar1 * K + kb + ac1, &As[c1 * 8]);
    load_lds16(Bblk + (size_t)ar0 * K + kb + ac0, &Bs[c0 * 8]);
    load_lds16(Bblk + (size_t)ar1 * K + kb + ac1, &Bs[c1 * 8]);
    __syncthreads();
    bh8 afrag[4], bfrag[4];
#pragma unroll
    for (int i = 0; i < 4; ++i) {
      afrag[i] = *(const bh8*)&As[(wm * 64 + i * 16 + r16) * BKK + krow];
      bfrag[i] = *(const bh8*)&Bs[(wn * 64 + i * 16 + r16) * BKK + krow];
    }
#pragma unroll
    for (int i = 0; i < 4; ++i)
#pragma unroll
      for (int j = 0; j < 4; ++j)
        acc[i][j] = __builtin_amdgcn_mfma_f32_16x16x32_bf16(afrag[i], bfrag[j], acc[i][j], 0, 0, 0);
    __syncthreads();
  }

  int r4 = (lane >> 4) * 4, cn = lane & 15;
#pragma unroll
  for (int i = 0; i < 4; ++i) {
#pragma unroll
    for (int j = 0; j < 4; ++j) {
      int col = bn * BN + wn * 64 + j * 16 + cn;
#pragma unroll
      for (int rr = 0; rr < 4; ++rr) {
        int row = bm * BM + wm * 64 + i * 16 + r4 + rr;
        size_t idx = (size_t)row * N + col;
        float val = acc[i][j][rr];
        if (EPI == 0) {
          Cbf[idx] = f32_to_bf16(val);
        } else if (EPI == 1) {
          Cbf[idx] = f32_to_bf16(1.f / (1.f + expf(-val)));
        } else if (EPI == 2) {
          C[idx] = aux1[idx] + val;
        } else if (EPI == 3) {
          float t = val > 0.f ? val : 0.f;
          Cbf[idx] = f32_to_bf16(t * t);
        } else {
          C[idx] = aux1[idx] + bf16_to_f32(aux2b[idx]) * val;
        }
      }
    }
  }
}

// ---------------- host launcher ----------------
extern "C" void kernel_launch(void* const* d_in, const int* in_sizes, int n_in,
                              void* d_out, int out_size, void* d_ws, size_t ws_size,
                              hipStream_t stream) {
  const float* x        = (const float*)d_in[0];
  const float* ln_att_g = (const float*)d_in[1];
  const float* ln_att_b = (const float*)d_in[2];
  const float* ln_ffn_g = (const float*)d_in[3];
  const float* ln_ffn_b = (const float*)d_in[4];
  const float* td       = (const float*)d_in[5];
  const float* tf       = (const float*)d_in[6];
  const float* amk      = (const float*)d_in[7];
  const float* amv      = (const float*)d_in[8];
  const float* amr      = (const float*)d_in[9];
  const float* att_wk   = (const float*)d_in[10];
  const float* att_wv   = (const float*)d_in[11];
  const float* att_wr   = (const float*)d_in[12];
  const float* att_wo   = (const float*)d_in[13];
  const float* fmk      = (const float*)d_in[14];
  const float* fmr      = (const float*)d_in[15];
  const float* ffn_wk   = (const float*)d_in[16];
  const float* ffn_wv   = (const float*)d_in[17];
  const float* ffn_wr   = (const float*)d_in[18];
  float* out = (float*)d_out;
  (void)in_sizes; (void)n_in; (void)out_size;

  // ---- workspace budget check ----
  const size_t WBYTES  = 4 * ((size_t)DSZ * DSZ * 2)      // wkT wvT wrT woT
                       + (size_t)FFN * DSZ * 2            // fwkT
                       + (size_t)DSZ * FFN * 2            // fwvT
                       + (size_t)DSZ * DSZ * 2;           // fwrT
  const size_t BUF     = (size_t)MROWS * DSZ * 2;         // 32 MB bf16
  const size_t NEEDED  = WBYTES + 4 * BUF + 2 * BUF;      // A,B,C,D + E(64MB)
  if (ws_size < NEEDED) return;

  char* ws = (char*)d_ws;
  size_t off = 0;
  auto take = [&](size_t bytes) { char* p = ws + off; off += (bytes + 255) & ~(size_t)255; return p; };

  unsigned short* wkT  = (unsigned short*)take((size_t)DSZ * DSZ * 2);
  unsigned short* wvT  = (unsigned short*)take((size_t)DSZ * DSZ * 2);
  unsigned short* wrT  = (unsigned short*)take((size_t)DSZ * DSZ * 2);
  unsigned short* woT  = (unsigned short*)take((size_t)DSZ * DSZ * 2);
  unsigned short* fwkT = (unsigned short*)take((size_t)FFN * DSZ * 2);  // 4096 x 1024
  unsigned short* fwvT = (unsigned short*)take((size_t)DSZ * FFN * 2);  // 1024 x 4096
  unsigned short* fwrT = (unsigned short*)take((size_t)DSZ * DSZ * 2);
  unsigned short* bufA = (unsigned short*)take(BUF);
  unsigned short* bufB = (unsigned short*)take(BUF);
  unsigned short* bufC = (unsigned short*)take(BUF);
  unsigned short* bufD = (unsigned short*)take(BUF);
  char*           eReg = take(2 * BUF);                   // E: 64 MB, dual use
  unsigned short* kf = bufC;                              // spans C + D + E = 128 MB (ffn phase)

  // WKV chunk-state arrays live in E (dead during attention phase): 6 x 1 MB
  float* sP = (float*)eReg;
  float* sQ = sP + WKV_STATES;
  float* sO = sQ + WKV_STATES;
  float* pP = sO + WKV_STATES;
  float* pQ = pP + WKV_STATES;
  float* pO = pQ + WKV_STATES;

  dim3 tb(32, 8);
  transpose_bf16<<<dim3(DSZ / 32, DSZ / 32), tb, 0, stream>>>(att_wk, wkT, DSZ, DSZ);
  transpose_bf16<<<dim3(DSZ / 32, DSZ / 32), tb, 0, stream>>>(att_wv, wvT, DSZ, DSZ);
  transpose_bf16<<<dim3(DSZ / 32, DSZ / 32), tb, 0, stream>>>(att_wr, wrT, DSZ, DSZ);
  transpose_bf16<<<dim3(DSZ / 32, DSZ / 32), tb, 0, stream>>>(att_wo, woT, DSZ, DSZ);
  transpose_bf16<<<dim3(FFN / 32, DSZ / 32), tb, 0, stream>>>(ffn_wk, fwkT, DSZ, FFN);
  transpose_bf16<<<dim3(DSZ / 32, FFN / 32), tb, 0, stream>>>(ffn_wv, fwvT, FFN, DSZ);
  transpose_bf16<<<dim3(DSZ / 32, DSZ / 32), tb, 0, stream>>>(ffn_wr, fwrT, DSZ, DSZ);

  // --- attention branch ---
  // A=xk B=xv C=xr
  lnmix_att<<<MROWS, 256, 0, stream>>>(x, ln_att_g, ln_att_b, amk, amv, amr, bufA, bufB, bufC);
  // D=k, then v into A, r into B, rw into C
  gemm_bt<0><<<dim3(DSZ / BN, MROWS / BM), 256, 0, stream>>>(bufA, wkT, nullptr, bufD, nullptr, nullptr, MROWS, DSZ, DSZ);
  gemm_bt<0><<<dim3(DSZ / BN, MROWS / BM), 256, 0, stream>>>(bufB, wvT, nullptr, bufA, nullptr, nullptr, MROWS, DSZ, DSZ);
  gemm_bt<1><<<dim3(DSZ / BN, MROWS / BM), 256, 0, stream>>>(bufC, wrT, nullptr, bufB, nullptr, nullptr, MROWS, DSZ, DSZ);
  // chunked WKV: k=bufD v=bufA r=bufB -> rw=bufC
  wkv_pass1<<<WKV_STATES / 256, 256, 0, stream>>>(bufD, bufA, td, sP, sQ, sO);
  wkv_combine<<<(BB * DSZ) / 256, 256, 0, stream>>>(sP, sQ, sO, td, pP, pQ, pO);
  wkv_pass3<<<WKV_STATES / 256, 256, 0, stream>>>(bufD, bufA, bufB, td, tf, pP, pQ, pO, bufC);
  gemm_bt<2><<<dim3(DSZ / BN, MROWS / BM), 256, 0, stream>>>(bufC, woT, out, nullptr, x, nullptr, MROWS, DSZ, DSZ);

  // --- ffn branch ---
  // A=xk2 B=xr2
  lnmix_ffn<<<MROWS, 256, 0, stream>>>(out, ln_ffn_g, ln_ffn_b, fmk, fmr, bufA, bufB);
  // kf = C..E (128 MB) — overwrites wkv state arrays (dead now)
  gemm_bt<3><<<dim3(FFN / BN, MROWS / BM), 256, 0, stream>>>(bufA, fwkT, nullptr, kf, nullptr, nullptr, MROWS, FFN, DSZ);
  // rf -> A (bf16)
  gemm_bt<1><<<dim3(DSZ / BN, MROWS / BM), 256, 0, stream>>>(bufB, fwrT, nullptr, bufA, nullptr, nullptr, MROWS, DSZ, DSZ);
  // out = out + rf * (kf @ ffn_wv)
  gemm_bt<4><<<dim3(DSZ / BN, MROWS / BM), 256, 0, stream>>>(kf, fwvT, out, nullptr, out, bufA, MROWS, DSZ, FFN);
}

// Round 4
// 697.518 us; speedup vs baseline: 2.3022x; 1.3544x over previous
//
#include <hip/hip_runtime.h>
#include <cstdint>
#include <cstddef>

// ---------------- problem constants ----------------
#define BB   8
#define LLEN 2048
#define DSZ  1024
#define FFN  4096
#define MROWS (BB*LLEN)   // 16384
#define EPSLN 1e-5f
#define WKV_C 32
#define WKV_S (LLEN/WKV_C)
#define WKV_STATES (BB*WKV_C*DSZ)

typedef __bf16 bh8 __attribute__((ext_vector_type(8)));
typedef float  f32x4 __attribute__((ext_vector_type(4)));

__device__ __forceinline__ unsigned short f32_to_bf16(float f) {
  unsigned int u = __float_as_uint(f);
  u += 0x7FFFu + ((u >> 16) & 1u);
  return (unsigned short)(u >> 16);
}
__device__ __forceinline__ float bf16_to_f32(unsigned short u) {
  return __uint_as_float(((unsigned int)u) << 16);
}

__device__ __forceinline__ void load_lds16(const void* g, void* l) {
  __builtin_amdgcn_global_load_lds((const __attribute__((address_space(1))) void*)g,
                                   (__attribute__((address_space(3))) void*)l, 16, 0, 0);
}

#define RAW_BAR() asm volatile("s_barrier" ::: "memory")
#define WAIT_VM6() asm volatile("s_waitcnt vmcnt(6)" ::: "memory")
#define WAIT_VM0() asm volatile("s_waitcnt vmcnt(0)" ::: "memory")
#define WAIT_LGKM0() asm volatile("s_waitcnt lgkmcnt(0)" ::: "memory")

// ---------------- weight transpose + f32->bf16 ----------------
__global__ __launch_bounds__(256) void transpose_bf16(const float* __restrict__ W,
                                                      unsigned short* __restrict__ Wt,
                                                      int K, int N) {
  __shared__ float tile[32][33];
  int n0 = blockIdx.x * 32, k0 = blockIdx.y * 32;
  int tx = threadIdx.x, ty = threadIdx.y;
#pragma unroll
  for (int j = 0; j < 32; j += 8)
    tile[ty + j][tx] = W[(size_t)(k0 + ty + j) * N + n0 + tx];
  __syncthreads();
#pragma unroll
  for (int j = 0; j < 32; j += 8)
    Wt[(size_t)(n0 + ty + j) * K + k0 + tx] = f32_to_bf16(tile[tx][ty + j]);
}

// ---------------- fused LayerNorm + time-shift mix (att) ----------------
__global__ __launch_bounds__(256) void lnmix_att(const float* __restrict__ x,
                                                 const float* __restrict__ g,
                                                 const float* __restrict__ bb,
                                                 const float* __restrict__ mk,
                                                 const float* __restrict__ mv,
                                                 const float* __restrict__ mr,
                                                 unsigned short* __restrict__ xk,
                                                 unsigned short* __restrict__ xv,
                                                 unsigned short* __restrict__ xr) {
  int row = blockIdx.x;
  int t = row & (LLEN - 1);
  int tid = threadIdx.x;
  float4 vc = ((const float4*)(x + (size_t)row * DSZ))[tid];
  float4 vp = make_float4(0.f, 0.f, 0.f, 0.f);
  if (t > 0) vp = ((const float4*)(x + (size_t)(row - 1) * DSZ))[tid];
  float sc = vc.x + vc.y + vc.z + vc.w;
  float qc = vc.x * vc.x + vc.y * vc.y + vc.z * vc.z + vc.w * vc.w;
  float sp = vp.x + vp.y + vp.z + vp.w;
  float qp = vp.x * vp.x + vp.y * vp.y + vp.z * vp.z + vp.w * vp.w;
#pragma unroll
  for (int off = 32; off; off >>= 1) {
    sc += __shfl_down(sc, off); qc += __shfl_down(qc, off);
    sp += __shfl_down(sp, off); qp += __shfl_down(qp, off);
  }
  __shared__ float red[16];
  int lane = tid & 63, w = tid >> 6;
  if (lane == 0) { red[w] = sc; red[4 + w] = qc; red[8 + w] = sp; red[12 + w] = qp; }
  __syncthreads();
  if (tid < 4) red[tid * 4] = red[tid * 4] + red[tid * 4 + 1] + red[tid * 4 + 2] + red[tid * 4 + 3];
  __syncthreads();
  const float invD = 1.f / DSZ;
  float mc = red[0] * invD, rc = rsqrtf(red[4] * invD - mc * mc + EPSLN);
  float mp = red[8] * invD, rp = rsqrtf(red[12] * invD - mp * mp + EPSLN);
  float4 G = ((const float4*)g)[tid], Bv = ((const float4*)bb)[tid];
  float c[4] = { vc.x, vc.y, vc.z, vc.w };
  float p[4] = { vp.x, vp.y, vp.z, vp.w };
  float Ga[4] = { G.x, G.y, G.z, G.w };
  float Ba[4] = { Bv.x, Bv.y, Bv.z, Bv.w };
  float4 K = ((const float4*)mk)[tid];
  float4 V = ((const float4*)mv)[tid];
  float4 R = ((const float4*)mr)[tid];
  float Ka[4] = { K.x, K.y, K.z, K.w };
  float Va[4] = { V.x, V.y, V.z, V.w };
  float Ra[4] = { R.x, R.y, R.z, R.w };
  ushort4 ok, ov, orr;
  unsigned short* okp = &ok.x; unsigned short* ovp = &ov.x; unsigned short* orp = &orr.x;
#pragma unroll
  for (int e = 0; e < 4; ++e) {
    float hc = (c[e] - mc) * rc * Ga[e] + Ba[e];
    float hp = (t > 0) ? (p[e] - mp) * rp * Ga[e] + Ba[e] : 0.f;
    okp[e] = f32_to_bf16(hc * Ka[e] + hp * (1.f - Ka[e]));
    ovp[e] = f32_to_bf16(hc * Va[e] + hp * (1.f - Va[e]));
    orp[e] = f32_to_bf16(hc * Ra[e] + hp * (1.f - Ra[e]));
  }
  size_t e4 = (size_t)row * DSZ + tid * 4;
  *(ushort4*)(xk + e4) = ok;
  *(ushort4*)(xv + e4) = ov;
  *(ushort4*)(xr + e4) = orr;
}

// ---------------- fused LayerNorm + time-shift mix (ffn) ----------------
__global__ __launch_bounds__(256) void lnmix_ffn(const float* __restrict__ x,
                                                 const float* __restrict__ g,
                                                 const float* __restrict__ bb,
                                                 const float* __restrict__ mk,
                                                 const float* __restrict__ mr,
                                                 unsigned short* __restrict__ xk,
                                                 unsigned short* __restrict__ xr) {
  int row = blockIdx.x;
  int t = row & (LLEN - 1);
  int tid = threadIdx.x;
  float4 vc = ((const float4*)(x + (size_t)row * DSZ))[tid];
  float4 vp = make_float4(0.f, 0.f, 0.f, 0.f);
  if (t > 0) vp = ((const float4*)(x + (size_t)(row - 1) * DSZ))[tid];
  float sc = vc.x + vc.y + vc.z + vc.w;
  float qc = vc.x * vc.x + vc.y * vc.y + vc.z * vc.z + vc.w * vc.w;
  float sp = vp.x + vp.y + vp.z + vp.w;
  float qp = vp.x * vp.x + vp.y * vp.y + vp.z * vp.z + vp.w * vp.w;
#pragma unroll
  for (int off = 32; off; off >>= 1) {
    sc += __shfl_down(sc, off); qc += __shfl_down(qc, off);
    sp += __shfl_down(sp, off); qp += __shfl_down(qp, off);
  }
  __shared__ float red[16];
  int lane = tid & 63, w = tid >> 6;
  if (lane == 0) { red[w] = sc; red[4 + w] = qc; red[8 + w] = sp; red[12 + w] = qp; }
  __syncthreads();
  if (tid < 4) red[tid * 4] = red[tid * 4] + red[tid * 4 + 1] + red[tid * 4 + 2] + red[tid * 4 + 3];
  __syncthreads();
  const float invD = 1.f / DSZ;
  float mc = red[0] * invD, rc = rsqrtf(red[4] * invD - mc * mc + EPSLN);
  float mp = red[8] * invD, rp = rsqrtf(red[12] * invD - mp * mp + EPSLN);
  float4 G = ((const float4*)g)[tid], Bv = ((const float4*)bb)[tid];
  float c[4] = { vc.x, vc.y, vc.z, vc.w };
  float p[4] = { vp.x, vp.y, vp.z, vp.w };
  float Ga[4] = { G.x, G.y, G.z, G.w };
  float Ba[4] = { Bv.x, Bv.y, Bv.z, Bv.w };
  float4 K = ((const float4*)mk)[tid];
  float4 R = ((const float4*)mr)[tid];
  float Ka[4] = { K.x, K.y, K.z, K.w };
  float Ra[4] = { R.x, R.y, R.z, R.w };
  ushort4 ok, orr;
  unsigned short* okp = &ok.x; unsigned short* orp = &orr.x;
#pragma unroll
  for (int e = 0; e < 4; ++e) {
    float hc = (c[e] - mc) * rc * Ga[e] + Ba[e];
    float hp = (t > 0) ? (p[e] - mp) * rp * Ga[e] + Ba[e] : 0.f;
    okp[e] = f32_to_bf16(hc * Ka[e] + hp * (1.f - Ka[e]));
    orp[e] = f32_to_bf16(hc * Ra[e] + hp * (1.f - Ra[e]));
  }
  size_t e4 = (size_t)row * DSZ + tid * 4;
  *(ushort4*)(xk + e4) = ok;
  *(ushort4*)(xr + e4) = orr;
}

// ---------------- WKV chunked scan ----------------
__global__ __launch_bounds__(256) void wkv_pass1(const unsigned short* __restrict__ kk,
                                                 const unsigned short* __restrict__ vv,
                                                 const float* __restrict__ td,
                                                 float* __restrict__ sP,
                                                 float* __restrict__ sQ,
                                                 float* __restrict__ sO) {
  int gid = blockIdx.x * 256 + threadIdx.x;
  int d  = gid & (DSZ - 1);
  int bc = gid >> 10;
  int c  = bc & (WKV_C - 1);
  int b  = bc >> 5;
  float w = -expf(td[d]);
  size_t base = ((size_t)b * LLEN + (size_t)c * WKV_S) * DSZ + d;
  float p = 0.f, q = 0.f, o = -1e38f;
  float kt = bf16_to_f32(kk[base]);
  float vt = bf16_to_f32(vv[base]);
  for (int t = 0; t < WKV_S; ++t) {
    float kn = 0.f, vn = 0.f;
    if (t < WKV_S - 1) {
      size_t nxt = base + ((size_t)(t + 1) << 10);
      kn = bf16_to_f32(kk[nxt]); vn = bf16_to_f32(vv[nxt]);
    }
    float ow  = o + w;
    float no2 = fmaxf(ow, kt);
    float A2  = expf(ow - no2);
    float B2  = expf(kt - no2);
    p = A2 * p + B2 * vt;
    q = A2 * q + B2;
    o = no2;
    kt = kn; vt = vn;
  }
  sP[gid] = p; sQ[gid] = q; sO[gid] = o;
}

__global__ __launch_bounds__(256) void wkv_combine(const float* __restrict__ sP,
                                                   const float* __restrict__ sQ,
                                                   const float* __restrict__ sO,
                                                   const float* __restrict__ td,
                                                   float* __restrict__ pP,
                                                   float* __restrict__ pQ,
                                                   float* __restrict__ pO) {
  int gid = blockIdx.x * 256 + threadIdx.x;
  int d = gid & (DSZ - 1);
  int b = gid >> 10;
  float w = -expf(td[d]);
  float Sw = (float)WKV_S * w;
  float p = 0.f, q = 0.f, o = -1e38f;
  for (int c = 0; c < WKV_C; ++c) {
    size_t idx = (((size_t)b * WKV_C + c) << 10) + d;
    pP[idx] = p; pQ[idx] = q; pO[idx] = o;
    float lp = sP[idx], lq = sQ[idx], lo = sO[idx];
    float oin = o + Sw;
    float no  = fmaxf(oin, lo);
    float Ai  = expf(oin - no);
    float Al  = expf(lo - no);
    p = Ai * p + Al * lp;
    q = Ai * q + Al * lq;
    o = no;
  }
}

__global__ __launch_bounds__(256) void wkv_pass3(const unsigned short* __restrict__ kk,
                                                 const unsigned short* __restrict__ vv,
                                                 const unsigned short* __restrict__ rr,
                                                 const float* __restrict__ td,
                                                 const float* __restrict__ tf,
                                                 const float* __restrict__ pP,
                                                 const float* __restrict__ pQ,
                                                 const float* __restrict__ pO,
                                                 unsigned short* __restrict__ rw) {
  int gid = blockIdx.x * 256 + threadIdx.x;
  int d  = gid & (DSZ - 1);
  int bc = gid >> 10;
  int c  = bc & (WKV_C - 1);
  int b  = bc >> 5;
  float w = -expf(td[d]);
  float u = tf[d];
  float p = pP[gid], q = pQ[gid], o = pO[gid];
  size_t base = ((size_t)b * LLEN + (size_t)c * WKV_S) * DSZ + d;
  float kt = bf16_to_f32(kk[base]);
  float vt = bf16_to_f32(vv[base]);
  float rt = bf16_to_f32(rr[base]);
  for (int t = 0; t < WKV_S; ++t) {
    float kn = 0.f, vn = 0.f, rn = 0.f;
    if (t < WKV_S - 1) {
      size_t nxt = base + ((size_t)(t + 1) << 10);
      kn = bf16_to_f32(kk[nxt]); vn = bf16_to_f32(vv[nxt]); rn = bf16_to_f32(rr[nxt]);
    }
    float uk = u + kt;
    float no = fmaxf(o, uk);
    float A  = expf(o - no);
    float Bc = expf(uk - no);
    float out = (A * p + Bc * vt) / (A * q + Bc);
    rw[base + ((size_t)t << 10)] = f32_to_bf16(rt * out);
    float ow  = o + w;
    float no2 = fmaxf(ow, kt);
    float A2  = expf(ow - no2);
    float B2  = expf(kt - no2);
    p = A2 * p + B2 * vt;
    q = A2 * q + B2;
    o = no2;
    kt = kn; vt = vn; rt = rn;
  }
}

// ============ 256x256 8-phase bf16 MFMA GEMM: C(MxN) = A(MxK) * Bt(NxK)^T ============
// 512 threads = 8 waves (2M x 4N), per-wave 128x64 output, BK=64, LDS 128 KiB dbuf.
// T2 swizzle: LDS(row, chunk) holds global(row, chunk ^ (row&7)); chunks are 16B.
// EPI: 0 Cbf=bf16(acc) | 1 Cbf=bf16(sigmoid) | 2 C=aux1+acc | 3 Cbf=bf16(relu^2) | 4 C=aux1+bf16(aux2b)*acc

// stage one 128-row x 64-col half-tile: 2 x global_load_lds(16B) per thread
__device__ __forceinline__ void stage_half(const unsigned short* __restrict__ gsrc,
                                           int Kd, unsigned char* lds_base,
                                           int lane, int wid) {
  int gcol = (((lane & 7) ^ (lane >> 3)) << 3);   // swizzled source chunk
  int grow = lane >> 3;
#pragma unroll
  for (int j = 0; j < 2; ++j) {
    int win = wid * 2 + j;                         // 0..15 (1 KiB windows)
    const unsigned short* src = gsrc + (size_t)(win * 8 + grow) * Kd + gcol;
    load_lds16(src, lds_base + win * 1024 + lane * 16);
  }
}

template <int EPI>
__global__ __launch_bounds__(512, 2) void gemm256(const unsigned short* __restrict__ A,
                                                  const unsigned short* __restrict__ Bt,
                                                  float* __restrict__ C,
                                                  unsigned short* __restrict__ Cbf,
                                                  const float* __restrict__ aux1,
                                                  const unsigned short* __restrict__ aux2b,
                                                  int M, int N, int K) {
  extern __shared__ unsigned char sm[];            // 131072 bytes
  unsigned char* smA = sm;                         // [buf:2][row:256][chunk:8][16B]
  unsigned char* smB = sm + 65536;

  const int tid  = threadIdx.x;
  const int lane = tid & 63;
  const int wid  = tid >> 6;
  const int wr   = wid >> 2;                       // 0..1 (M)
  const int wc   = wid & 3;                        // 0..3 (N)

  // XCD-aware bijective block swizzle (nwg % 8 == 0 for all our launches)
  int nwg = gridDim.x;
  int gx  = N >> 8;
  int wg  = blockIdx.x;
  int swzid = ((nwg & 7) == 0) ? ((wg & 7) * (nwg >> 3) + (wg >> 3)) : wg;
  int bn = swzid % gx, bm = swzid / gx;

  const unsigned short* Ab = A  + (size_t)bm * 256 * K;
  const unsigned short* Bb = Bt + (size_t)bn * 256 * K;

  const int nk = K >> 6;                           // K-tiles of 64

  // per-lane ds_read swizzled chunk offsets (bytes): chunk = (kh*4+g) ^ (lane&7)
  const int r15 = lane & 15;
  const int sw0 = ((((lane >> 4)    ) ^ (lane & 7)) << 4);
  const int sw1 = (((4 | (lane >> 4)) ^ (lane & 7)) << 4);
  const int aRow = wr * 16384 + r15 * 128;         // + mi*2048 + sw + buf*32768
  const int bRow = wc * 8192  + r15 * 128;         // + nj*2048 + sw + buf*32768

  f32x4 acc[8][4];
#pragma unroll
  for (int i = 0; i < 8; ++i)
#pragma unroll
    for (int j = 0; j < 4; ++j)
#pragma unroll
      for (int e = 0; e < 4; ++e) acc[i][j][e] = 0.f;

  // ---- prologue: A0[0] A1[0] B0[0] B1[0] A0[1] A1[1] B0[1]  (14 loads/thread) ----
  stage_half(Ab,                 K, smA,                 lane, wid);
  stage_half(Ab + (size_t)128*K, K, smA + 16384,         lane, wid);
  stage_half(Bb,                 K, smB,                 lane, wid);
  stage_half(Bb + (size_t)128*K, K, smB + 16384,         lane, wid);
  if (nk > 1) {
    stage_half(Ab + 64,                 K, smA + 32768,         lane, wid);
    stage_half(Ab + (size_t)128*K + 64, K, smA + 32768 + 16384, lane, wid);
    stage_half(Bb + 64,                 K, smB + 32768,         lane, wid);
  }
  WAIT_VM6();
  RAW_BAR();

  for (int t = 0; t < nk; ++t) {
    const int buf  = (t & 1) * 32768;
    const int bufn = ((t + 1) & 1) * 32768;        // = buf of t+2 is `buf` itself
    const int kb1  = (t + 1) << 6;
    const int kb2  = (t + 2) << 6;

    // ---------------- phase 1: all frag ds_reads + stage B1[t+1] ----------------
    bh8 a[8][2], b[4][2];
#pragma unroll
    for (int mi = 0; mi < 8; ++mi) {
      a[mi][0] = *(const bh8*)(smA + buf + aRow + mi * 2048 + sw0);
      a[mi][1] = *(const bh8*)(smA + buf + aRow + mi * 2048 + sw1);
    }
#pragma unroll
    for (int nj = 0; nj < 4; ++nj) {
      b[nj][0] = *(const bh8*)(smB + buf + bRow + nj * 2048 + sw0);
      b[nj][1] = *(const bh8*)(smB + buf + bRow + nj * 2048 + sw1);
    }
    if (t + 1 < nk)
      stage_half(Bb + (size_t)128*K + kb1, K, smB + bufn + 16384, lane, wid);
    RAW_BAR();
    __builtin_amdgcn_s_setprio(1);
#pragma unroll
    for (int mi = 0; mi < 4; ++mi)
#pragma unroll
      for (int nj = 0; nj < 2; ++nj) {
        acc[mi][nj] = __builtin_amdgcn_mfma_f32_16x16x32_bf16(a[mi][0], b[nj][0], acc[mi][nj], 0, 0, 0);
        acc[mi][nj] = __builtin_amdgcn_mfma_f32_16x16x32_bf16(a[mi][1], b[nj][1], acc[mi][nj], 0, 0, 0);
      }
    __builtin_amdgcn_s_setprio(0);
    WAIT_LGKM0();                                  // all 24 frag reads retired before anyone stages into buf
    RAW_BAR();

    // ---------------- phase 2: stage A0[t+2] ----------------
    if (t + 2 < nk) stage_half(Ab + kb2, K, smA + buf, lane, wid);
    RAW_BAR();
    __builtin_amdgcn_s_setprio(1);
#pragma unroll
    for (int mi = 0; mi < 4; ++mi)
#pragma unroll
      for (int nj = 2; nj < 4; ++nj) {
        acc[mi][nj] = __builtin_amdgcn_mfma_f32_16x16x32_bf16(a[mi][0], b[nj][0], acc[mi][nj], 0, 0, 0);
        acc[mi][nj] = __builtin_amdgcn_mfma_f32_16x16x32_bf16(a[mi][1], b[nj][1], acc[mi][nj], 0, 0, 0);
      }
    __builtin_amdgcn_s_setprio(0);
    RAW_BAR();

    // ---------------- phase 3: stage A1[t+2] ----------------
    if (t + 2 < nk) stage_half(Ab + (size_t)128*K + kb2, K, smA + buf + 16384, lane, wid);
    RAW_BAR();
    __builtin_amdgcn_s_setprio(1);
#pragma unroll
    for (int mi = 4; mi < 8; ++mi)
#pragma unroll
      for (int nj = 0; nj < 2; ++nj) {
        acc[mi][nj] = __builtin_amdgcn_mfma_f32_16x16x32_bf16(a[mi][0], b[nj][0], acc[mi][nj], 0, 0, 0);
        acc[mi][nj] = __builtin_amdgcn_mfma_f32_16x16x32_bf16(a[mi][1], b[nj][1], acc[mi][nj], 0, 0, 0);
      }
    __builtin_amdgcn_s_setprio(0);
    RAW_BAR();

    // ---------------- phase 4: stage B0[t+2], boundary vmcnt ----------------
    if (t + 2 < nk) stage_half(Bb + kb2, K, smB + buf, lane, wid);
    RAW_BAR();
    __builtin_amdgcn_s_setprio(1);
#pragma unroll
    for (int mi = 4; mi < 8; ++mi)
#pragma unroll
      for (int nj = 2; nj < 4; ++nj) {
        acc[mi][nj] = __builtin_amdgcn_mfma_f32_16x16x32_bf16(a[mi][0], b[nj][0], acc[mi][nj], 0, 0, 0);
        acc[mi][nj] = __builtin_amdgcn_mfma_f32_16x16x32_bf16(a[mi][1], b[nj][1], acc[mi][nj], 0, 0, 0);
      }
    __builtin_amdgcn_s_setprio(0);
    if (t + 2 < nk) { WAIT_VM6(); } else { WAIT_VM0(); }
    RAW_BAR();
  }

  // ---------------- epilogue ----------------
  const int r4 = (lane >> 4) * 4, cn = lane & 15;
#pragma unroll
  for (int mi = 0; mi < 8; ++mi) {
#pragma unroll
    for (int nj = 0; nj < 4; ++nj) {
      int col = bn * 256 + wc * 64 + nj * 16 + cn;
#pragma unroll
      for (int e = 0; e < 4; ++e) {
        int row = bm * 256 + wr * 128 + mi * 16 + r4 + e;
        size_t idx = (size_t)row * N + col;
        float val = acc[mi][nj][e];
        if (EPI == 0) {
          Cbf[idx] = f32_to_bf16(val);
        } else if (EPI == 1) {
          Cbf[idx] = f32_to_bf16(1.f / (1.f + expf(-val)));
        } else if (EPI == 2) {
          C[idx] = aux1[idx] + val;
        } else if (EPI == 3) {
          float tt = val > 0.f ? val : 0.f;
          Cbf[idx] = f32_to_bf16(tt * tt);
        } else {
          C[idx] = aux1[idx] + bf16_to_f32(aux2b[idx]) * val;
        }
      }
    }
  }
}

// ---------------- host launcher ----------------
extern "C" void kernel_launch(void* const* d_in, const int* in_sizes, int n_in,
                              void* d_out, int out_size, void* d_ws, size_t ws_size,
                              hipStream_t stream) {
  const float* x        = (const float*)d_in[0];
  const float* ln_att_g = (const float*)d_in[1];
  const float* ln_att_b = (const float*)d_in[2];
  const float* ln_ffn_g = (const float*)d_in[3];
  const float* ln_ffn_b = (const float*)d_in[4];
  const float* td       = (const float*)d_in[5];
  const float* tf       = (const float*)d_in[6];
  const float* amk      = (const float*)d_in[7];
  const float* amv      = (const float*)d_in[8];
  const float* amr      = (const float*)d_in[9];
  const float* att_wk   = (const float*)d_in[10];
  const float* att_wv   = (const float*)d_in[11];
  const float* att_wr   = (const float*)d_in[12];
  const float* att_wo   = (const float*)d_in[13];
  const float* fmk      = (const float*)d_in[14];
  const float* fmr      = (const float*)d_in[15];
  const float* ffn_wk   = (const float*)d_in[16];
  const float* ffn_wv   = (const float*)d_in[17];
  const float* ffn_wr   = (const float*)d_in[18];
  float* out = (float*)d_out;
  (void)in_sizes; (void)n_in; (void)out_size;

  const size_t WBYTES  = 4 * ((size_t)DSZ * DSZ * 2)
                       + (size_t)FFN * DSZ * 2
                       + (size_t)DSZ * FFN * 2
                       + (size_t)DSZ * DSZ * 2;
  const size_t BUF     = (size_t)MROWS * DSZ * 2;
  const size_t NEEDED  = WBYTES + 4 * BUF + 2 * BUF;
  if (ws_size < NEEDED) return;

  char* ws = (char*)d_ws;
  size_t off = 0;
  auto take = [&](size_t bytes) { char* p = ws + off; off += (bytes + 255) & ~(size_t)255; return p; };

  unsigned short* wkT  = (unsigned short*)take((size_t)DSZ * DSZ * 2);
  unsigned short* wvT  = (unsigned short*)take((size_t)DSZ * DSZ * 2);
  unsigned short* wrT  = (unsigned short*)take((size_t)DSZ * DSZ * 2);
  unsigned short* woT  = (unsigned short*)take((size_t)DSZ * DSZ * 2);
  unsigned short* fwkT = (unsigned short*)take((size_t)FFN * DSZ * 2);
  unsigned short* fwvT = (unsigned short*)take((size_t)DSZ * FFN * 2);
  unsigned short* fwrT = (unsigned short*)take((size_t)DSZ * DSZ * 2);
  unsigned short* bufA = (unsigned short*)take(BUF);
  unsigned short* bufB = (unsigned short*)take(BUF);
  unsigned short* bufC = (unsigned short*)take(BUF);
  unsigned short* bufD = (unsigned short*)take(BUF);
  char*           eReg = take(2 * BUF);
  unsigned short* kf = bufC;                       // spans C + D + E (ffn phase)

  float* sP = (float*)eReg;
  float* sQ = sP + WKV_STATES;
  float* sO = sQ + WKV_STATES;
  float* pP = sO + WKV_STATES;
  float* pQ = pP + WKV_STATES;
  float* pO = pQ + WKV_STATES;

  dim3 tb(32, 8);
  transpose_bf16<<<dim3(DSZ / 32, DSZ / 32), tb, 0, stream>>>(att_wk, wkT, DSZ, DSZ);
  transpose_bf16<<<dim3(DSZ / 32, DSZ / 32), tb, 0, stream>>>(att_wv, wvT, DSZ, DSZ);
  transpose_bf16<<<dim3(DSZ / 32, DSZ / 32), tb, 0, stream>>>(att_wr, wrT, DSZ, DSZ);
  transpose_bf16<<<dim3(DSZ / 32, DSZ / 32), tb, 0, stream>>>(att_wo, woT, DSZ, DSZ);
  transpose_bf16<<<dim3(FFN / 32, DSZ / 32), tb, 0, stream>>>(ffn_wk, fwkT, DSZ, FFN);
  transpose_bf16<<<dim3(DSZ / 32, FFN / 32), tb, 0, stream>>>(ffn_wv, fwvT, FFN, DSZ);
  transpose_bf16<<<dim3(DSZ / 32, DSZ / 32), tb, 0, stream>>>(ffn_wr, fwrT, DSZ, DSZ);

  const int LDSB = 131072;
  const int G1   = (MROWS / 256) * (DSZ / 256);    // 256 blocks
  const int G2   = (MROWS / 256) * (FFN / 256);    // 1024 blocks

  // --- attention branch ---
  lnmix_att<<<MROWS, 256, 0, stream>>>(x, ln_att_g, ln_att_b, amk, amv, amr, bufA, bufB, bufC);
  gemm256<0><<<G1, 512, LDSB, stream>>>(bufA, wkT, nullptr, bufD, nullptr, nullptr, MROWS, DSZ, DSZ);
  gemm256<0><<<G1, 512, LDSB, stream>>>(bufB, wvT, nullptr, bufA, nullptr, nullptr, MROWS, DSZ, DSZ);
  gemm256<1><<<G1, 512, LDSB, stream>>>(bufC, wrT, nullptr, bufB, nullptr, nullptr, MROWS, DSZ, DSZ);
  wkv_pass1<<<WKV_STATES / 256, 256, 0, stream>>>(bufD, bufA, td, sP, sQ, sO);
  wkv_combine<<<(BB * DSZ) / 256, 256, 0, stream>>>(sP, sQ, sO, td, pP, pQ, pO);
  wkv_pass3<<<WKV_STATES / 256, 256, 0, stream>>>(bufD, bufA, bufB, td, tf, pP, pQ, pO, bufC);
  gemm256<2><<<G1, 512, LDSB, stream>>>(bufC, woT, out, nullptr, x, nullptr, MROWS, DSZ, DSZ);

  // --- ffn branch ---
  lnmix_ffn<<<MROWS, 256, 0, stream>>>(out, ln_ffn_g, ln_ffn_b, fmk, fmr, bufA, bufB);
  gemm256<3><<<G2, 512, LDSB, stream>>>(bufA, fwkT, nullptr, kf, nullptr, nullptr, MROWS, FFN, DSZ);
  gemm256<1><<<G1, 512, LDSB, stream>>>(bufB, fwrT, nullptr, bufA, nullptr, nullptr, MROWS, DSZ, DSZ);
  gemm256<4><<<G1, 512, LDSB, stream>>>(kf, fwvT, out, nullptr, out, bufA, MROWS, DSZ, FFN);
}

// Round 5
// 685.470 us; speedup vs baseline: 2.3427x; 1.0176x over previous
//
#include <hip/hip_runtime.h>
#include <cstdint>
#include <cstddef>

// ---------------- problem constants ----------------
#define BB   8
#define LLEN 2048
#define DSZ  1024
#define FFN  4096
#define MROWS (BB*LLEN)   // 16384
#define EPSLN 1e-5f
#define WKV_C 32
#define WKV_S (LLEN/WKV_C)
#define WKV_STATES (BB*WKV_C*DSZ)

typedef __bf16 bh8 __attribute__((ext_vector_type(8)));
typedef float  f32x4 __attribute__((ext_vector_type(4)));

__device__ __forceinline__ unsigned short f32_to_bf16(float f) {
  unsigned int u = __float_as_uint(f);
  u += 0x7FFFu + ((u >> 16) & 1u);
  return (unsigned short)(u >> 16);
}
__device__ __forceinline__ float bf16_to_f32(unsigned short u) {
  return __uint_as_float(((unsigned int)u) << 16);
}
__device__ __forceinline__ float bf16_lo(unsigned int u) {
  return __uint_as_float(u << 16);
}
__device__ __forceinline__ float bf16_hi(unsigned int u) {
  return __uint_as_float(u & 0xFFFF0000u);
}
__device__ __forceinline__ unsigned int pack_bf16(float lo, float hi) {
  return (unsigned int)f32_to_bf16(lo) | ((unsigned int)f32_to_bf16(hi) << 16);
}

__device__ __forceinline__ void load_lds16(const void* g, void* l) {
  __builtin_amdgcn_global_load_lds((const __attribute__((address_space(1))) void*)g,
                                   (__attribute__((address_space(3))) void*)l, 16, 0, 0);
}

#define RAW_BAR() asm volatile("s_barrier" ::: "memory")
#define WAIT_VM6() asm volatile("s_waitcnt vmcnt(6)" ::: "memory")
#define WAIT_VM0() asm volatile("s_waitcnt vmcnt(0)" ::: "memory")

// ---------------- weight transpose + f32->bf16 ----------------
__global__ __launch_bounds__(256) void transpose_bf16(const float* __restrict__ W,
                                                      unsigned short* __restrict__ Wt,
                                                      int K, int N) {
  __shared__ float tile[32][33];
  int n0 = blockIdx.x * 32, k0 = blockIdx.y * 32;
  int tx = threadIdx.x, ty = threadIdx.y;
#pragma unroll
  for (int j = 0; j < 32; j += 8)
    tile[ty + j][tx] = W[(size_t)(k0 + ty + j) * N + n0 + tx];
  __syncthreads();
#pragma unroll
  for (int j = 0; j < 32; j += 8)
    Wt[(size_t)(n0 + ty + j) * K + k0 + tx] = f32_to_bf16(tile[tx][ty + j]);
}

// ---------------- fused LayerNorm + time-shift mix (att) ----------------
__global__ __launch_bounds__(256) void lnmix_att(const float* __restrict__ x,
                                                 const float* __restrict__ g,
                                                 const float* __restrict__ bb,
                                                 const float* __restrict__ mk,
                                                 const float* __restrict__ mv,
                                                 const float* __restrict__ mr,
                                                 unsigned short* __restrict__ xk,
                                                 unsigned short* __restrict__ xv,
                                                 unsigned short* __restrict__ xr) {
  int row = blockIdx.x;
  int t = row & (LLEN - 1);
  int tid = threadIdx.x;
  float4 vc = ((const float4*)(x + (size_t)row * DSZ))[tid];
  float4 vp = make_float4(0.f, 0.f, 0.f, 0.f);
  if (t > 0) vp = ((const float4*)(x + (size_t)(row - 1) * DSZ))[tid];
  float sc = vc.x + vc.y + vc.z + vc.w;
  float qc = vc.x * vc.x + vc.y * vc.y + vc.z * vc.z + vc.w * vc.w;
  float sp = vp.x + vp.y + vp.z + vp.w;
  float qp = vp.x * vp.x + vp.y * vp.y + vp.z * vp.z + vp.w * vp.w;
#pragma unroll
  for (int off = 32; off; off >>= 1) {
    sc += __shfl_down(sc, off); qc += __shfl_down(qc, off);
    sp += __shfl_down(sp, off); qp += __shfl_down(qp, off);
  }
  __shared__ float red[16];
  int lane = tid & 63, w = tid >> 6;
  if (lane == 0) { red[w] = sc; red[4 + w] = qc; red[8 + w] = sp; red[12 + w] = qp; }
  __syncthreads();
  if (tid < 4) red[tid * 4] = red[tid * 4] + red[tid * 4 + 1] + red[tid * 4 + 2] + red[tid * 4 + 3];
  __syncthreads();
  const float invD = 1.f / DSZ;
  float mc = red[0] * invD, rc = rsqrtf(red[4] * invD - mc * mc + EPSLN);
  float mp = red[8] * invD, rp = rsqrtf(red[12] * invD - mp * mp + EPSLN);
  float4 G = ((const float4*)g)[tid], Bv = ((const float4*)bb)[tid];
  float c[4] = { vc.x, vc.y, vc.z, vc.w };
  float p[4] = { vp.x, vp.y, vp.z, vp.w };
  float Ga[4] = { G.x, G.y, G.z, G.w };
  float Ba[4] = { Bv.x, Bv.y, Bv.z, Bv.w };
  float4 K = ((const float4*)mk)[tid];
  float4 V = ((const float4*)mv)[tid];
  float4 R = ((const float4*)mr)[tid];
  float Ka[4] = { K.x, K.y, K.z, K.w };
  float Va[4] = { V.x, V.y, V.z, V.w };
  float Ra[4] = { R.x, R.y, R.z, R.w };
  ushort4 ok, ov, orr;
  unsigned short* okp = &ok.x; unsigned short* ovp = &ov.x; unsigned short* orp = &orr.x;
#pragma unroll
  for (int e = 0; e < 4; ++e) {
    float hc = (c[e] - mc) * rc * Ga[e] + Ba[e];
    float hp = (t > 0) ? (p[e] - mp) * rp * Ga[e] + Ba[e] : 0.f;
    okp[e] = f32_to_bf16(hc * Ka[e] + hp * (1.f - Ka[e]));
    ovp[e] = f32_to_bf16(hc * Va[e] + hp * (1.f - Va[e]));
    orp[e] = f32_to_bf16(hc * Ra[e] + hp * (1.f - Ra[e]));
  }
  size_t e4 = (size_t)row * DSZ + tid * 4;
  *(ushort4*)(xk + e4) = ok;
  *(ushort4*)(xv + e4) = ov;
  *(ushort4*)(xr + e4) = orr;
}

// ---------------- fused LayerNorm + time-shift mix (ffn) ----------------
__global__ __launch_bounds__(256) void lnmix_ffn(const float* __restrict__ x,
                                                 const float* __restrict__ g,
                                                 const float* __restrict__ bb,
                                                 const float* __restrict__ mk,
                                                 const float* __restrict__ mr,
                                                 unsigned short* __restrict__ xk,
                                                 unsigned short* __restrict__ xr) {
  int row = blockIdx.x;
  int t = row & (LLEN - 1);
  int tid = threadIdx.x;
  float4 vc = ((const float4*)(x + (size_t)row * DSZ))[tid];
  float4 vp = make_float4(0.f, 0.f, 0.f, 0.f);
  if (t > 0) vp = ((const float4*)(x + (size_t)(row - 1) * DSZ))[tid];
  float sc = vc.x + vc.y + vc.z + vc.w;
  float qc = vc.x * vc.x + vc.y * vc.y + vc.z * vc.z + vc.w * vc.w;
  float sp = vp.x + vp.y + vp.z + vp.w;
  float qp = vp.x * vp.x + vp.y * vp.y + vp.z * vp.z + vp.w * vp.w;
#pragma unroll
  for (int off = 32; off; off >>= 1) {
    sc += __shfl_down(sc, off); qc += __shfl_down(qc, off);
    sp += __shfl_down(sp, off); qp += __shfl_down(qp, off);
  }
  __shared__ float red[16];
  int lane = tid & 63, w = tid >> 6;
  if (lane == 0) { red[w] = sc; red[4 + w] = qc; red[8 + w] = sp; red[12 + w] = qp; }
  __syncthreads();
  if (tid < 4) red[tid * 4] = red[tid * 4] + red[tid * 4 + 1] + red[tid * 4 + 2] + red[tid * 4 + 3];
  __syncthreads();
  const float invD = 1.f / DSZ;
  float mc = red[0] * invD, rc = rsqrtf(red[4] * invD - mc * mc + EPSLN);
  float mp = red[8] * invD, rp = rsqrtf(red[12] * invD - mp * mp + EPSLN);
  float4 G = ((const float4*)g)[tid], Bv = ((const float4*)bb)[tid];
  float c[4] = { vc.x, vc.y, vc.z, vc.w };
  float p[4] = { vp.x, vp.y, vp.z, vp.w };
  float Ga[4] = { G.x, G.y, G.z, G.w };
  float Ba[4] = { Bv.x, Bv.y, Bv.z, Bv.w };
  float4 K = ((const float4*)mk)[tid];
  float4 R = ((const float4*)mr)[tid];
  float Ka[4] = { K.x, K.y, K.z, K.w };
  float Ra[4] = { R.x, R.y, R.z, R.w };
  ushort4 ok, orr;
  unsigned short* okp = &ok.x; unsigned short* orp = &orr.x;
#pragma unroll
  for (int e = 0; e < 4; ++e) {
    float hc = (c[e] - mc) * rc * Ga[e] + Ba[e];
    float hp = (t > 0) ? (p[e] - mp) * rp * Ga[e] + Ba[e] : 0.f;
    okp[e] = f32_to_bf16(hc * Ka[e] + hp * (1.f - Ka[e]));
    orp[e] = f32_to_bf16(hc * Ra[e] + hp * (1.f - Ra[e]));
  }
  size_t e4 = (size_t)row * DSZ + tid * 4;
  *(ushort4*)(xk + e4) = ok;
  *(ushort4*)(xr + e4) = orr;
}

// ---------------- WKV chunked scan (2 channels per thread) ----------------
__global__ __launch_bounds__(256) void wkv_pass1(const unsigned int* __restrict__ kk2,
                                                 const unsigned int* __restrict__ vv2,
                                                 const float* __restrict__ td,
                                                 float* __restrict__ sP,
                                                 float* __restrict__ sQ,
                                                 float* __restrict__ sO) {
  int gid = blockIdx.x * 256 + threadIdx.x;       // 0 .. WKV_STATES/2-1
  int d2 = gid & 511;
  int bc = gid >> 9;
  int c  = bc & (WKV_C - 1);
  int b  = bc >> 5;
  int d0 = d2 * 2;
  float w0 = -expf(td[d0]), w1 = -expf(td[d0 + 1]);
  size_t base = ((size_t)b * LLEN + (size_t)c * WKV_S) * 512 + d2;   // uint units
  float p0 = 0.f, q0 = 0.f, o0 = -1e38f;
  float p1 = 0.f, q1 = 0.f, o1 = -1e38f;
  unsigned int kc = kk2[base], vc = vv2[base];
  unsigned int kA = 0, vA = 0, kB = 0, vB = 0;
  if (WKV_S > 1) { kA = kk2[base + 512]; vA = vv2[base + 512]; }
  for (int t = 0; t < WKV_S; ++t) {
    if (t + 2 < WKV_S) {
      size_t nxt = base + (size_t)(t + 2) * 512;
      kB = kk2[nxt]; vB = vv2[nxt];
    } else { kB = 0; vB = 0; }
    {
      float kt = bf16_lo(kc), vt = bf16_lo(vc);
      float ow = o0 + w0;
      float no2 = fmaxf(ow, kt);
      float A2 = expf(ow - no2), B2 = expf(kt - no2);
      p0 = A2 * p0 + B2 * vt; q0 = A2 * q0 + B2; o0 = no2;
    }
    {
      float kt = bf16_hi(kc), vt = bf16_hi(vc);
      float ow = o1 + w1;
      float no2 = fmaxf(ow, kt);
      float A2 = expf(ow - no2), B2 = expf(kt - no2);
      p1 = A2 * p1 + B2 * vt; q1 = A2 * q1 + B2; o1 = no2;
    }
    kc = kA; vc = vA; kA = kB; vA = vB;
  }
  int sidx = (bc << 10) + d0;
  sP[sidx] = p0; sP[sidx + 1] = p1;
  sQ[sidx] = q0; sQ[sidx + 1] = q1;
  sO[sidx] = o0; sO[sidx + 1] = o1;
}

__global__ __launch_bounds__(256) void wkv_combine(const float* __restrict__ sP,
                                                   const float* __restrict__ sQ,
                                                   const float* __restrict__ sO,
                                                   const float* __restrict__ td,
                                                   float* __restrict__ pP,
                                                   float* __restrict__ pQ,
                                                   float* __restrict__ pO) {
  int gid = blockIdx.x * 256 + threadIdx.x;
  int d = gid & (DSZ - 1);
  int b = gid >> 10;
  float w = -expf(td[d]);
  float Sw = (float)WKV_S * w;
  float p = 0.f, q = 0.f, o = -1e38f;
  for (int c = 0; c < WKV_C; ++c) {
    size_t idx = (((size_t)b * WKV_C + c) << 10) + d;
    pP[idx] = p; pQ[idx] = q; pO[idx] = o;
    float lp = sP[idx], lq = sQ[idx], lo = sO[idx];
    float oin = o + Sw;
    float no  = fmaxf(oin, lo);
    float Ai  = expf(oin - no);
    float Al  = expf(lo - no);
    p = Ai * p + Al * lp;
    q = Ai * q + Al * lq;
    o = no;
  }
}

__global__ __launch_bounds__(256) void wkv_pass3(const unsigned int* __restrict__ kk2,
                                                 const unsigned int* __restrict__ vv2,
                                                 const unsigned int* __restrict__ rr2,
                                                 const float* __restrict__ td,
                                                 const float* __restrict__ tf,
                                                 const float* __restrict__ pP,
                                                 const float* __restrict__ pQ,
                                                 const float* __restrict__ pO,
                                                 unsigned int* __restrict__ rw2) {
  int gid = blockIdx.x * 256 + threadIdx.x;
  int d2 = gid & 511;
  int bc = gid >> 9;
  int c  = bc & (WKV_C - 1);
  int b  = bc >> 5;
  int d0 = d2 * 2;
  float w0 = -expf(td[d0]), w1 = -expf(td[d0 + 1]);
  float u0 = tf[d0], u1 = tf[d0 + 1];
  int sidx = (bc << 10) + d0;
  float p0 = pP[sidx], q0 = pQ[sidx], o0 = pO[sidx];
  float p1 = pP[sidx + 1], q1 = pQ[sidx + 1], o1 = pO[sidx + 1];
  size_t base = ((size_t)b * LLEN + (size_t)c * WKV_S) * 512 + d2;
  unsigned int kc = kk2[base], vc = vv2[base], rc = rr2[base];
  unsigned int kA = 0, vA = 0, rA = 0, kB = 0, vB = 0, rB = 0;
  if (WKV_S > 1) { kA = kk2[base + 512]; vA = vv2[base + 512]; rA = rr2[base + 512]; }
  for (int t = 0; t < WKV_S; ++t) {
    if (t + 2 < WKV_S) {
      size_t nxt = base + (size_t)(t + 2) * 512;
      kB = kk2[nxt]; vB = vv2[nxt]; rB = rr2[nxt];
    } else { kB = 0; vB = 0; rB = 0; }
    float out0, out1;
    {
      float kt = bf16_lo(kc), vt = bf16_lo(vc);
      float uk = u0 + kt;
      float no = fmaxf(o0, uk);
      float A  = expf(o0 - no), Bc = expf(uk - no);
      out0 = (A * p0 + Bc * vt) / (A * q0 + Bc);
      float ow = o0 + w0;
      float no2 = fmaxf(ow, kt);
      float A2 = expf(ow - no2), B2 = expf(kt - no2);
      p0 = A2 * p0 + B2 * vt; q0 = A2 * q0 + B2; o0 = no2;
    }
    {
      float kt = bf16_hi(kc), vt = bf16_hi(vc);
      float uk = u1 + kt;
      float no = fmaxf(o1, uk);
      float A  = expf(o1 - no), Bc = expf(uk - no);
      out1 = (A * p1 + Bc * vt) / (A * q1 + Bc);
      float ow = o1 + w1;
      float no2 = fmaxf(ow, kt);
      float A2 = expf(ow - no2), B2 = expf(kt - no2);
      p1 = A2 * p1 + B2 * vt; q1 = A2 * q1 + B2; o1 = no2;
    }
    rw2[base + (size_t)t * 512] = pack_bf16(bf16_lo(rc) * out0, bf16_hi(rc) * out1);
    kc = kA; vc = vA; rc = rA; kA = kB; vA = vB; rA = rB;
  }
}

// ============ 256x256 4-phase bf16 MFMA GEMM: C(MxN) = A(MxK) * Bt(NxK)^T ============
// 512 threads = 8 waves (2M x 4N), per-wave 128x64 output, BK=64, LDS 128 KiB dbuf.
// Per-phase spread ds_reads (12/4/8/0) consumed in-phase; staging placed so each LDS
// region is overwritten only in a phase AFTER its last read was consumed (barrier-ordered).
// EPI: 0 Cbf=bf16(acc) | 1 Cbf=bf16(sigmoid) | 2 C=aux1+acc | 3 Cbf=bf16(relu^2) | 4 C=aux1+bf16(aux2b)*acc

__device__ __forceinline__ void stage_half(const unsigned short* __restrict__ gsrc,
                                           int Kd, unsigned char* lds_base,
                                           int lane, int wid) {
  int gcol = (((lane & 7) ^ (lane >> 3)) << 3);   // swizzled source chunk
  int grow = lane >> 3;
#pragma unroll
  for (int j = 0; j < 2; ++j) {
    int win = wid * 2 + j;                         // 0..15 (1 KiB windows)
    const unsigned short* src = gsrc + (size_t)(win * 8 + grow) * Kd + gcol;
    load_lds16(src, lds_base + win * 1024 + lane * 16);
  }
}

template <int EPI>
__global__ __launch_bounds__(512, 2) void gemm256(const unsigned short* __restrict__ A,
                                                  const unsigned short* __restrict__ Bt,
                                                  float* __restrict__ C,
                                                  unsigned short* __restrict__ Cbf,
                                                  const float* __restrict__ aux1,
                                                  const unsigned short* __restrict__ aux2b,
                                                  int M, int N, int K) {
  extern __shared__ unsigned char sm[];            // 131072 bytes
  unsigned char* smA = sm;                         // [buf:2][row:256][128B]
  unsigned char* smB = sm + 65536;

  const int tid  = threadIdx.x;
  const int lane = tid & 63;
  const int wid  = tid >> 6;
  const int wr   = wid >> 2;                       // 0..1 (M)
  const int wc   = wid & 3;                        // 0..3 (N)

  int nwg = gridDim.x;
  int gx  = N >> 8;
  int wg  = blockIdx.x;
  int swzid = ((nwg & 7) == 0) ? ((wg & 7) * (nwg >> 3) + (wg >> 3)) : wg;
  int bn = swzid % gx, bm = swzid / gx;

  const unsigned short* Ab = A  + (size_t)bm * 256 * K;
  const unsigned short* Bb = Bt + (size_t)bn * 256 * K;

  const int nk = K >> 6;

  const int r15 = lane & 15;
  const int sw0 = ((((lane >> 4)    ) ^ (lane & 7)) << 4);
  const int sw1 = (((4 | (lane >> 4)) ^ (lane & 7)) << 4);
  const int aRow = wr * 16384 + r15 * 128;
  const int bRow = wc * 8192  + r15 * 128;

  f32x4 acc[8][4];
#pragma unroll
  for (int i = 0; i < 8; ++i)
#pragma unroll
    for (int j = 0; j < 4; ++j)
#pragma unroll
      for (int e = 0; e < 4; ++e) acc[i][j][e] = 0.f;

  // ---- prologue: A0[0] A1[0] B0[0] B1[0], then B0[1] A0[1] A1[1] ----
  stage_half(Ab,                 K, smA,                 lane, wid);
  stage_half(Ab + (size_t)128*K, K, smA + 16384,         lane, wid);
  stage_half(Bb,                 K, smB,                 lane, wid);
  stage_half(Bb + (size_t)128*K, K, smB + 16384,         lane, wid);
  if (nk > 1) {
    stage_half(Bb + 64,                 K, smB + 32768,         lane, wid);
    stage_half(Ab + 64,                 K, smA + 32768,         lane, wid);
    stage_half(Ab + (size_t)128*K + 64, K, smA + 32768 + 16384, lane, wid);
    WAIT_VM6();
  } else {
    WAIT_VM0();
  }
  RAW_BAR();

  bh8 a03[4][2], a47[4][2], b01[2][2], b23[2][2];

  for (int t = 0; t < nk; ++t) {
    const int buf  = (t & 1) * 32768;
    const int bufn = buf ^ 32768;
    const int kb1  = (t + 1) << 6;
    const int kb2  = (t + 2) << 6;

    // ---- phase 1: read a0-3, b0-1; stage B1[t+1]; MFMA Q1 ----
#pragma unroll
    for (int mi = 0; mi < 4; ++mi) {
      a03[mi][0] = *(const bh8*)(smA + buf + aRow + mi * 2048 + sw0);
      a03[mi][1] = *(const bh8*)(smA + buf + aRow + mi * 2048 + sw1);
    }
#pragma unroll
    for (int nj = 0; nj < 2; ++nj) {
      b01[nj][0] = *(const bh8*)(smB + buf + bRow + nj * 2048 + sw0);
      b01[nj][1] = *(const bh8*)(smB + buf + bRow + nj * 2048 + sw1);
    }
    if (t + 1 < nk)
      stage_half(Bb + (size_t)128*K + kb1, K, smB + bufn + 16384, lane, wid);
    RAW_BAR();
    __builtin_amdgcn_s_setprio(1);
#pragma unroll
    for (int mi = 0; mi < 4; ++mi)
#pragma unroll
      for (int nj = 0; nj < 2; ++nj) {
        acc[mi][nj] = __builtin_amdgcn_mfma_f32_16x16x32_bf16(a03[mi][0], b01[nj][0], acc[mi][nj], 0, 0, 0);
        acc[mi][nj] = __builtin_amdgcn_mfma_f32_16x16x32_bf16(a03[mi][1], b01[nj][1], acc[mi][nj], 0, 0, 0);
      }
    __builtin_amdgcn_s_setprio(0);
    RAW_BAR();

    // ---- phase 2: read b2-3; MFMA Q2 ----
#pragma unroll
    for (int nj = 0; nj < 2; ++nj) {
      b23[nj][0] = *(const bh8*)(smB + buf + bRow + (nj + 2) * 2048 + sw0);
      b23[nj][1] = *(const bh8*)(smB + buf + bRow + (nj + 2) * 2048 + sw1);
    }
    RAW_BAR();
    __builtin_amdgcn_s_setprio(1);
#pragma unroll
    for (int mi = 0; mi < 4; ++mi)
#pragma unroll
      for (int nj = 0; nj < 2; ++nj) {
        acc[mi][nj + 2] = __builtin_amdgcn_mfma_f32_16x16x32_bf16(a03[mi][0], b23[nj][0], acc[mi][nj + 2], 0, 0, 0);
        acc[mi][nj + 2] = __builtin_amdgcn_mfma_f32_16x16x32_bf16(a03[mi][1], b23[nj][1], acc[mi][nj + 2], 0, 0, 0);
      }
    __builtin_amdgcn_s_setprio(0);
    RAW_BAR();

    // ---- phase 3: read a4-7; stage B0[t+2]; MFMA Q3 ----
#pragma unroll
    for (int mi = 0; mi < 4; ++mi) {
      a47[mi][0] = *(const bh8*)(smA + buf + aRow + (mi + 4) * 2048 + sw0);
      a47[mi][1] = *(const bh8*)(smA + buf + aRow + (mi + 4) * 2048 + sw1);
    }
    if (t + 2 < nk) stage_half(Bb + kb2, K, smB + buf, lane, wid);
    RAW_BAR();
    __builtin_amdgcn_s_setprio(1);
#pragma unroll
    for (int mi = 0; mi < 4; ++mi)
#pragma unroll
      for (int nj = 0; nj < 2; ++nj) {
        acc[mi + 4][nj] = __builtin_amdgcn_mfma_f32_16x16x32_bf16(a47[mi][0], b01[nj][0], acc[mi + 4][nj], 0, 0, 0);
        acc[mi + 4][nj] = __builtin_amdgcn_mfma_f32_16x16x32_bf16(a47[mi][1], b01[nj][1], acc[mi + 4][nj], 0, 0, 0);
      }
    __builtin_amdgcn_s_setprio(0);
    RAW_BAR();

    // ---- phase 4: stage A0[t+2], A1[t+2]; MFMA Q4; boundary vmcnt ----
    if (t + 2 < nk) {
      stage_half(Ab + kb2,                 K, smA + buf,         lane, wid);
      stage_half(Ab + (size_t)128*K + kb2, K, smA + buf + 16384, lane, wid);
    }
    RAW_BAR();
    __builtin_amdgcn_s_setprio(1);
#pragma unroll
    for (int mi = 0; mi < 4; ++mi)
#pragma unroll
      for (int nj = 0; nj < 2; ++nj) {
        acc[mi + 4][nj + 2] = __builtin_amdgcn_mfma_f32_16x16x32_bf16(a47[mi][0], b23[nj][0], acc[mi + 4][nj + 2], 0, 0, 0);
        acc[mi + 4][nj + 2] = __builtin_amdgcn_mfma_f32_16x16x32_bf16(a47[mi][1], b23[nj][1], acc[mi + 4][nj + 2], 0, 0, 0);
      }
    __builtin_amdgcn_s_setprio(0);
    if (t + 2 < nk) { WAIT_VM6(); } else { WAIT_VM0(); }
    RAW_BAR();
  }

  // ---------------- epilogue ----------------
  const int r4 = (lane >> 4) * 4, cn = lane & 15;
#pragma unroll
  for (int mi = 0; mi < 8; ++mi) {
#pragma unroll
    for (int nj = 0; nj < 4; ++nj) {
      int col = bn * 256 + wc * 64 + nj * 16 + cn;
#pragma unroll
      for (int e = 0; e < 4; ++e) {
        int row = bm * 256 + wr * 128 + mi * 16 + r4 + e;
        size_t idx = (size_t)row * N + col;
        float val = acc[mi][nj][e];
        if (EPI == 0) {
          Cbf[idx] = f32_to_bf16(val);
        } else if (EPI == 1) {
          Cbf[idx] = f32_to_bf16(1.f / (1.f + expf(-val)));
        } else if (EPI == 2) {
          C[idx] = aux1[idx] + val;
        } else if (EPI == 3) {
          float tt = val > 0.f ? val : 0.f;
          Cbf[idx] = f32_to_bf16(tt * tt);
        } else {
          C[idx] = aux1[idx] + bf16_to_f32(aux2b[idx]) * val;
        }
      }
    }
  }
}

// ---------------- host launcher ----------------
extern "C" void kernel_launch(void* const* d_in, const int* in_sizes, int n_in,
                              void* d_out, int out_size, void* d_ws, size_t ws_size,
                              hipStream_t stream) {
  const float* x        = (const float*)d_in[0];
  const float* ln_att_g = (const float*)d_in[1];
  const float* ln_att_b = (const float*)d_in[2];
  const float* ln_ffn_g = (const float*)d_in[3];
  const float* ln_ffn_b = (const float*)d_in[4];
  const float* td       = (const float*)d_in[5];
  const float* tf       = (const float*)d_in[6];
  const float* amk      = (const float*)d_in[7];
  const float* amv      = (const float*)d_in[8];
  const float* amr      = (const float*)d_in[9];
  const float* att_wk   = (const float*)d_in[10];
  const float* att_wv   = (const float*)d_in[11];
  const float* att_wr   = (const float*)d_in[12];
  const float* att_wo   = (const float*)d_in[13];
  const float* fmk      = (const float*)d_in[14];
  const float* fmr      = (const float*)d_in[15];
  const float* ffn_wk   = (const float*)d_in[16];
  const float* ffn_wv   = (const float*)d_in[17];
  const float* ffn_wr   = (const float*)d_in[18];
  float* out = (float*)d_out;
  (void)in_sizes; (void)n_in; (void)out_size;

  const size_t WBYTES  = 4 * ((size_t)DSZ * DSZ * 2)
                       + (size_t)FFN * DSZ * 2
                       + (size_t)DSZ * FFN * 2
                       + (size_t)DSZ * DSZ * 2;
  const size_t BUF     = (size_t)MROWS * DSZ * 2;
  const size_t NEEDED  = WBYTES + 4 * BUF + 2 * BUF;
  if (ws_size < NEEDED) return;

  char* ws = (char*)d_ws;
  size_t off = 0;
  auto take = [&](size_t bytes) { char* p = ws + off; off += (bytes + 255) & ~(size_t)255; return p; };

  unsigned short* wkT  = (unsigned short*)take((size_t)DSZ * DSZ * 2);
  unsigned short* wvT  = (unsigned short*)take((size_t)DSZ * DSZ * 2);
  unsigned short* wrT  = (unsigned short*)take((size_t)DSZ * DSZ * 2);
  unsigned short* woT  = (unsigned short*)take((size_t)DSZ * DSZ * 2);
  unsigned short* fwkT = (unsigned short*)take((size_t)FFN * DSZ * 2);
  unsigned short* fwvT = (unsigned short*)take((size_t)DSZ * FFN * 2);
  unsigned short* fwrT = (unsigned short*)take((size_t)DSZ * DSZ * 2);
  unsigned short* bufA = (unsigned short*)take(BUF);
  unsigned short* bufB = (unsigned short*)take(BUF);
  unsigned short* bufC = (unsigned short*)take(BUF);
  unsigned short* bufD = (unsigned short*)take(BUF);
  char*           eReg = take(2 * BUF);
  unsigned short* kf = bufC;                       // spans C + D + E (ffn phase)

  float* sP = (float*)eReg;
  float* sQ = sP + WKV_STATES;
  float* sO = sQ + WKV_STATES;
  float* pP = sO + WKV_STATES;
  float* pQ = pP + WKV_STATES;
  float* pO = pQ + WKV_STATES;

  dim3 tb(32, 8);
  transpose_bf16<<<dim3(DSZ / 32, DSZ / 32), tb, 0, stream>>>(att_wk, wkT, DSZ, DSZ);
  transpose_bf16<<<dim3(DSZ / 32, DSZ / 32), tb, 0, stream>>>(att_wv, wvT, DSZ, DSZ);
  transpose_bf16<<<dim3(DSZ / 32, DSZ / 32), tb, 0, stream>>>(att_wr, wrT, DSZ, DSZ);
  transpose_bf16<<<dim3(DSZ / 32, DSZ / 32), tb, 0, stream>>>(att_wo, woT, DSZ, DSZ);
  transpose_bf16<<<dim3(FFN / 32, DSZ / 32), tb, 0, stream>>>(ffn_wk, fwkT, DSZ, FFN);
  transpose_bf16<<<dim3(DSZ / 32, FFN / 32), tb, 0, stream>>>(ffn_wv, fwvT, FFN, DSZ);
  transpose_bf16<<<dim3(DSZ / 32, DSZ / 32), tb, 0, stream>>>(ffn_wr, fwrT, DSZ, DSZ);

  const int LDSB = 131072;
  const int G1   = (MROWS / 256) * (DSZ / 256);    // 256 blocks
  const int G2   = (MROWS / 256) * (FFN / 256);    // 1024 blocks

  // --- attention branch ---
  lnmix_att<<<MROWS, 256, 0, stream>>>(x, ln_att_g, ln_att_b, amk, amv, amr, bufA, bufB, bufC);
  gemm256<0><<<G1, 512, LDSB, stream>>>(bufA, wkT, nullptr, bufD, nullptr, nullptr, MROWS, DSZ, DSZ);
  gemm256<0><<<G1, 512, LDSB, stream>>>(bufB, wvT, nullptr, bufA, nullptr, nullptr, MROWS, DSZ, DSZ);
  gemm256<1><<<G1, 512, LDSB, stream>>>(bufC, wrT, nullptr, bufB, nullptr, nullptr, MROWS, DSZ, DSZ);
  wkv_pass1<<<(WKV_STATES / 2) / 256, 256, 0, stream>>>((const unsigned int*)bufD, (const unsigned int*)bufA, td, sP, sQ, sO);
  wkv_combine<<<(BB * DSZ) / 256, 256, 0, stream>>>(sP, sQ, sO, td, pP, pQ, pO);
  wkv_pass3<<<(WKV_STATES / 2) / 256, 256, 0, stream>>>((const unsigned int*)bufD, (const unsigned int*)bufA, (const unsigned int*)bufB, td, tf, pP, pQ, pO, (unsigned int*)bufC);
  gemm256<2><<<G1, 512, LDSB, stream>>>(bufC, woT, out, nullptr, x, nullptr, MROWS, DSZ, DSZ);

  // --- ffn branch ---
  lnmix_ffn<<<MROWS, 256, 0, stream>>>(out, ln_ffn_g, ln_ffn_b, fmk, fmr, bufA, bufB);
  gemm256<3><<<G2, 512, LDSB, stream>>>(bufA, fwkT, nullptr, kf, nullptr, nullptr, MROWS, FFN, DSZ);
  gemm256<1><<<G1, 512, LDSB, stream>>>(bufB, fwrT, nullptr, bufA, nullptr, nullptr, MROWS, DSZ, DSZ);
  gemm256<4><<<G1, 512, LDSB, stream>>>(kf, fwvT, out, nullptr, out, bufA, MROWS, DSZ, FFN);
}